// Round 15
// baseline (4948.954 us; speedup 1.0000x reference)
//
#include <hip/hip_runtime.h>

typedef __attribute__((ext_vector_type(4))) float f32x4;
typedef __attribute__((ext_vector_type(8))) __bf16 bf16x8;
typedef __attribute__((ext_vector_type(4))) unsigned short us4;
typedef __attribute__((ext_vector_type(8))) unsigned short us8;

#define DEVI static __device__ __forceinline__

constexpr int C_   = 256;
constexpr int HW_  = 112 * 112;   // 12544
constexpr int M_   = 4 * HW_;     // 50176 tokens
constexpr int HID_ = 1024;

DEVI unsigned short f2bf(float f) {
  unsigned u = __float_as_uint(f);
  u += 0x7fffu + ((u >> 16) & 1u);
  return (unsigned short)(u >> 16);
}
DEVI float bf2f(unsigned short s) { return __uint_as_float(((unsigned)s) << 16); }
// tanh-form GELU via v_exp_f32 (~9 VALU vs ~25 for erff); max dev ~3e-4
DEVI float gelu_f(float x) {
  float u = x * (0.7978845608028654f + 0.0356774081363001f * x * x);
  float e = __expf(2.f * u);
  float t = 1.f - 2.f / (e + 1.f);
  return 0.5f * x * (1.f + t);
}

// ---------------- fp32 -> bf16 cast (weights) ----------------
__global__ void cast_bf16_kernel(const float* __restrict__ src,
                                 unsigned short* __restrict__ dst, int n4) {
  int i = blockIdx.x * 256 + threadIdx.x;
  if (i < n4) {
    f32x4 v = ((const f32x4*)src)[i];
    us4 o;
    o.x = f2bf(v.x); o.y = f2bf(v.y); o.z = f2bf(v.z); o.w = f2bf(v.w);
    ((us4*)dst)[i] = o;
  }
}

// ---------------- dw weights (blk, c, 9) -> (blk, 9, c) ----------------
__global__ void dwT_kernel(const float* __restrict__ w, float* __restrict__ wT) {
  int i = blockIdx.x * 256 + threadIdx.x;
  if (i < 2 * HID_ * 9) {
    int blkI = i / (HID_ * 9), rem = i % (HID_ * 9);
    int c = rem / 9, wi = rem % 9;
    wT[blkI * HID_ * 9 + wi * HID_ + c] = w[i];
  }
}

// ---------------- (B,C,HW) -> (B,HW,C) ----------------
__global__ void transpose_in_kernel(const float* __restrict__ x, float* __restrict__ t) {
  __shared__ float tile[32][33];
  int b = blockIdx.z;
  int p0 = blockIdx.x * 32, c0 = blockIdx.y * 32;
  int tx = threadIdx.x, ty = threadIdx.y;
  const float* xb = x + (size_t)b * C_ * HW_;
#pragma unroll
  for (int i = 0; i < 4; i++)
    tile[ty + 8 * i][tx] = xb[(size_t)(c0 + ty + 8 * i) * HW_ + p0 + tx];
  __syncthreads();
  float* tb = t + (size_t)b * HW_ * C_;
#pragma unroll
  for (int i = 0; i < 4; i++)
    tb[(size_t)(p0 + ty + 8 * i) * C_ + c0 + tx] = tile[tx][ty + 8 * i];
}

// ---------------- (B,HW,C) -> (B,C,HW) ----------------
__global__ void transpose_out_kernel(const float* __restrict__ t, float* __restrict__ out) {
  __shared__ float tile[32][33];
  int b = blockIdx.z;
  int p0 = blockIdx.x * 32, c0 = blockIdx.y * 32;
  int tx = threadIdx.x, ty = threadIdx.y;
  const float* tb = t + (size_t)b * HW_ * C_;
#pragma unroll
  for (int i = 0; i < 4; i++)
    tile[ty + 8 * i][tx] = tb[(size_t)(p0 + ty + 8 * i) * C_ + c0 + tx];
  __syncthreads();
  float* ob = out + (size_t)b * C_ * HW_;
#pragma unroll
  for (int i = 0; i < 4; i++)
    ob[(size_t)(c0 + ty + 8 * i) * HW_ + p0 + tx] = tile[tx][ty + 8 * i];
}

// ---------------- LayerNorm (fp32 in, bf16 out), one wave per row ----------------
__global__ void ln_kernel(const float* __restrict__ t, const float* __restrict__ g,
                          const float* __restrict__ bsh, unsigned short* __restrict__ out) {
  int row = blockIdx.x * 4 + (threadIdx.x >> 6);
  int lane = threadIdx.x & 63;
  const float* tr = t + (size_t)row * C_;
  f32x4 v = ((const f32x4*)tr)[lane];
  float s  = v.x + v.y + v.z + v.w;
  float s2 = v.x * v.x + v.y * v.y + v.z * v.z + v.w * v.w;
#pragma unroll
  for (int off = 1; off < 64; off <<= 1) {
    s  += __shfl_xor(s, off);
    s2 += __shfl_xor(s2, off);
  }
  float mean = s * (1.f / 256.f);
  float var  = s2 * (1.f / 256.f) - mean * mean;
  float rstd = rsqrtf(var + 1e-6f);
  f32x4 gg = ((const f32x4*)g)[lane];
  f32x4 bb = ((const f32x4*)bsh)[lane];
  us4 o;
  o.x = f2bf((v.x - mean) * rstd * gg.x + bb.x);
  o.y = f2bf((v.y - mean) * rstd * gg.y + bb.y);
  o.z = f2bf((v.z - mean) * rstd * gg.z + bb.z);
  o.w = f2bf((v.w - mean) * rstd * gg.w + bb.w);
  ((us4*)(out + (size_t)row * C_))[lane] = o;
}

// ---------------- GEMM: out(M,N) = A(M,K) * Wt(N,K)^T, bf16 in, fp32 acc ----------------
// 128x128 block tile, 4 waves (2x2, 64x64 each), 3 LDS buffers (48KB -> 3 blocks/CU),
// depth-2 prefetch, counted vmcnt(4). XCD-chunked swizzle for A-panel L2 reuse.
// bf16 epilogues (EPI 0/2) staged through LDS -> 16B/lane coalesced stores.
template <int EPI>
__global__ __launch_bounds__(256, 2) void gemm_kernel(
    const unsigned short* __restrict__ A, const unsigned short* __restrict__ Wt,
    const float* __restrict__ bias, const float* __restrict__ bng,
    const float* __restrict__ bnb, float* __restrict__ resid,
    unsigned short* __restrict__ outb, int N, int K) {
  // per buffer: A[128*32] shorts @0, B[128*32] shorts @4096; 8192 shorts = 16KB
  __shared__ unsigned short smem[3 * 8192];
  const int tid = threadIdx.x;
  const int wave = tid >> 6, lane = tid & 63;

  // XCD-chunked swizzle (all grids have nwg % 8 == 0); bn is the fast dim so
  // one XCD owns all bn-blocks of a run of bm -> A-panel fetched once per XCD.
  const int bnN = gridDim.x;
  const int nwg = bnN * gridDim.y;
  int wg = blockIdx.y * bnN + blockIdx.x;
  const int chunk = nwg >> 3;
  wg = (wg & 7) * chunk + (wg >> 3);
  const int bn = wg % bnN;
  const int bm = wg / bnN;

  const int wm = wave >> 1, wn = wave & 1;
  const int laneRow = lane >> 2;      // 0..15
  const int scol = (lane & 3) * 8;    // shorts (16B per lane)
  const size_t aBase = (size_t)bm * 128;
  const size_t bBase = (size_t)bn * 128;

  f32x4 acc[4][4];
#pragma unroll
  for (int i = 0; i < 4; i++)
#pragma unroll
    for (int j = 0; j < 4; j++) acc[i][j] = f32x4{0.f, 0.f, 0.f, 0.f};

  // 4 global_load_lds per wave per step (2 for A's 32 rows, 2 for B's 32 rows)
  auto stage = [&](int buf, int kt) {
    const int k0 = kt << 5;
    unsigned short* sb = smem + buf * 8192;
#pragma unroll
    for (int r = 0; r < 2; ++r) {
      int row = wave * 32 + r * 16 + laneRow;
      __builtin_amdgcn_global_load_lds(
          (const __attribute__((address_space(1))) void*)(A + (aBase + row) * K + k0 + scol),
          (__attribute__((address_space(3))) void*)(sb + row * 32 + scol), 16, 0, 0);
    }
#pragma unroll
    for (int r = 0; r < 2; ++r) {
      int row = wave * 32 + r * 16 + laneRow;
      __builtin_amdgcn_global_load_lds(
          (const __attribute__((address_space(1))) void*)(Wt + (bBase + row) * K + k0 + scol),
          (__attribute__((address_space(3))) void*)(sb + 4096 + row * 32 + scol), 16, 0, 0);
    }
  };

  const int nK = K >> 5;
  stage(0, 0);
  if (nK > 1) {
    stage(1, 1);
    asm volatile("s_waitcnt vmcnt(4)" ::: "memory");
  } else {
    asm volatile("s_waitcnt vmcnt(0)" ::: "memory");
  }
  __builtin_amdgcn_s_barrier();
  asm volatile("" ::: "memory");

  const int fr = lane & 15, kh = (lane >> 4) * 8;
  for (int kt = 0; kt < nK; ++kt) {
    const int cur = kt % 3;
    const bool more2 = (kt + 2 < nK);
    if (more2) stage((kt + 2) % 3, kt + 2);  // depth-2 prefetch flies over compute

    const unsigned short* sb = smem + cur * 8192;
    bf16x8 af[4], bfr[4];
#pragma unroll
    for (int mi = 0; mi < 4; mi++)
      af[mi] = *(const bf16x8*)(sb + (wm * 64 + mi * 16 + fr) * 32 + kh);
#pragma unroll
    for (int ni = 0; ni < 4; ni++)
      bfr[ni] = *(const bf16x8*)(sb + 4096 + (wn * 64 + ni * 16 + fr) * 32 + kh);
#pragma unroll
    for (int mi = 0; mi < 4; mi++)
#pragma unroll
      for (int ni = 0; ni < 4; ni++)
        acc[mi][ni] = __builtin_amdgcn_mfma_f32_16x16x32_bf16(af[mi], bfr[ni], acc[mi][ni], 0, 0, 0);

    if (kt + 1 < nK) {
      if (more2) {
        asm volatile("s_waitcnt vmcnt(4)" ::: "memory");  // retire tile kt+1 only
      } else {
        asm volatile("s_waitcnt vmcnt(0)" ::: "memory");  // boundary drain (once)
      }
      __builtin_amdgcn_s_barrier();
      asm volatile("" ::: "memory");
    }
  }

  const int r4 = (lane >> 4) * 4;
  const float bnrs = 0.9999950000374997f;  // rsqrt(1 + 1e-5)

  if (EPI == 0 || EPI == 2) {
    // --- staged bf16 epilogue: LDS tile [128][128] shorts with row-XOR swizzle ---
    __syncthreads();  // all waves done reading K-loop smem
    unsigned short* esm = smem;  // 16384 shorts = 32KB <= 48KB
#pragma unroll
    for (int ni = 0; ni < 4; ni++) {
      int cl = wn * 64 + ni * 16 + fr;       // local col 0..127
      int cg = bn * 128 + cl;                // global col
      float bval = bias[cg];
      float sc = 0.f, sh = 0.f;
      if (EPI == 2) { sc = bng[cg] * bnrs; sh = bnb[cg]; }
#pragma unroll
      for (int mi = 0; mi < 4; mi++) {
#pragma unroll
        for (int j = 0; j < 4; j++) {
          int row = wm * 64 + mi * 16 + r4 + j;
          float v = acc[mi][ni][j] + bval;
          if (EPI == 2) v = gelu_f(v * sc + sh);
          esm[row * 128 + (cl ^ (((row >> 2) & 3) << 4))] = f2bf(v);
        }
      }
    }
    __syncthreads();
#pragma unroll
    for (int it = 0; it < 8; it++) {
      int idx = it * 256 + tid;
      int row = idx >> 4;
      int c0 = (idx & 15) * 8;
      int c0s = c0 ^ (((row >> 2) & 3) << 4);
      us8 v = *(const us8*)(esm + row * 128 + c0s);
      *(us8*)(outb + (aBase + row) * (size_t)N + bn * 128 + c0) = v;
    }
  } else {
    // --- fp32 residual RMW (already 64B-coalesced) ---
#pragma unroll
    for (int ni = 0; ni < 4; ni++) {
      int cg = bn * 128 + wn * 64 + ni * 16 + fr;
      float bval = bias[cg];
      float sc = 0.f, sh = 0.f;
      if (EPI == 3) { sc = bng[cg] * bnrs; sh = bnb[cg]; }
#pragma unroll
      for (int mi = 0; mi < 4; mi++) {
#pragma unroll
        for (int j = 0; j < 4; j++) {
          size_t rg = aBase + wm * 64 + mi * 16 + r4 + j;
          float v = acc[mi][ni][j] + bval;
          if (EPI == 1) {
            resid[rg * 256 + cg] += v;
          } else {
            resid[rg * 256 + cg] += gelu_f(v * sc + sh);
          }
        }
      }
    }
  }
}

// ---------------- windowed attention, register-resident ----------------
// R14: K and V TIME-SHARE one 25KB LDS buffer (K live only in QK, V only in PV):
// stage K -> barrier -> QK -> barrier -> stage V into same buffer (softmax in
// registers overlaps V load latency) -> barrier -> PV.
// LDS 52 -> 27.8KB => 5 blocks/CU (VGPR 76 allows 6 waves/SIMD).
// R9/R10 lesson: keep f32 LDS + f32x4 o[8] (bf16-V/o32 restructure spilled).
__global__ __launch_bounds__(256, 2) void attn_kernel(const unsigned short* __restrict__ qkv,
                                                      const float* __restrict__ rpe,
                                                      unsigned short* __restrict__ y2) {
  __shared__ float kvs[4 * 49 * 32];   // K during QK phase, then V during PV
  __shared__ float rpet[4 * 169];      // [h_l][ridx]
  const int tid = threadIdx.x;
  const int blk = blockIdx.x;
  const int win = blk >> 1;
  const int hg = (blk & 1) * 4;
  const int b = win >> 8, rem = win & 255;
  const int ph = rem >> 4, pw = rem & 15;
  const size_t base = (size_t)b * HW_ + ph * 7 * 112 + pw * 7;

  // rpe for this block's 4 heads only
  for (int c = tid; c < 169 * 4; c += 256)
    rpet[(c & 3) * 169 + (c >> 2)] = rpe[(c >> 2) * 8 + hg + (c & 3)];
  // stage K (bf16 -> f32)
  for (int c = tid; c < 4 * 49 * 8; c += 256) {
    int h_l = c / (49 * 8);
    int r2 = c - h_l * (49 * 8);
    int tok = r2 >> 3, ch4 = r2 & 7;
    size_t m = base + (tok / 7) * 112 + (tok % 7);
    const unsigned short* kp = qkv + m * 768 + 256 + (hg + h_l) * 32 + ch4 * 4;
    us4 kv = *(const us4*)kp;
    float* kd = kvs + (h_l * 49 + tok) * 32 + ch4 * 4;
    kd[0] = bf2f(kv.x); kd[1] = bf2f(kv.y); kd[2] = bf2f(kv.z); kd[3] = bf2f(kv.w);
  }

  const int lane = tid & 63;
  const int h_l = tid >> 6;
  const int h = hg + h_l;
  const int qi = lane < 49 ? lane : 48;
  const size_t mq = base + (qi / 7) * 112 + (qi % 7);

  f32x4 q[8];
  {
    const unsigned short* qp = qkv + mq * 768 + h * 32;
    const float qsc = 0.17677669529663689f;  // 1/sqrt(32)
#pragma unroll
    for (int j = 0; j < 8; j++) {
      us4 v = *(const us4*)(qp + j * 4);
      q[j].x = bf2f(v.x) * qsc; q[j].y = bf2f(v.y) * qsc;
      q[j].z = bf2f(v.z) * qsc; q[j].w = bf2f(v.w) * qsc;
    }
  }
  __syncthreads();

  // S = q . K^T (wave-uniform LDS rows -> broadcast reads)
  float S[49];
  const float* kbase = kvs + h_l * 49 * 32;
#pragma unroll
  for (int ki = 0; ki < 49; ki++) {
    const f32x4* kr = (const f32x4*)(kbase + ki * 32);
    f32x4 a0 = {0.f, 0.f, 0.f, 0.f}, a1 = {0.f, 0.f, 0.f, 0.f};
#pragma unroll
    for (int j = 0; j < 4; j++) {
      a0 += q[2 * j] * kr[2 * j];
      a1 += q[2 * j + 1] * kr[2 * j + 1];
    }
    f32x4 as = a0 + a1;
    S[ki] = (as.x + as.z) + (as.y + as.w);
  }
  __syncthreads();  // all K reads done; buffer free for V

  // stage V into the SAME buffer; its load latency hides under the softmax below
  for (int c = tid; c < 4 * 49 * 8; c += 256) {
    int h_l2 = c / (49 * 8);
    int r2 = c - h_l2 * (49 * 8);
    int tok = r2 >> 3, ch4 = r2 & 7;
    size_t m = base + (tok / 7) * 112 + (tok % 7);
    const unsigned short* vp = qkv + m * 768 + 512 + (hg + h_l2) * 32 + ch4 * 4;
    us4 vv = *(const us4*)vp;
    float* vd = kvs + (h_l2 * 49 + tok) * 32 + ch4 * 4;
    vd[0] = bf2f(vv.x); vd[1] = bf2f(vv.y); vd[2] = bf2f(vv.z); vd[3] = bf2f(vv.w);
  }

  // softmax in registers (rpet is a separate LDS buffer, untouched by V stage)
  const int qr = qi / 7, qc = qi % 7;
  const float* rp = rpet + h_l * 169;
#pragma unroll
  for (int ki = 0; ki < 49; ki++) {
    int ridx = (qr - ki / 7 + 6) * 13 + (qc - ki % 7 + 6);
    S[ki] += rp[ridx];
  }
  float mx = S[0];
#pragma unroll
  for (int ki = 1; ki < 49; ki++) mx = fmaxf(mx, S[ki]);
  float sum = 0.f;
#pragma unroll
  for (int ki = 0; ki < 49; ki++) {
    float e = __expf(S[ki] - mx);
    S[ki] = e;
    sum += e;
  }
  float inv = 1.f / sum;
  __syncthreads();  // V staged

  f32x4 o[8];
#pragma unroll
  for (int j = 0; j < 8; j++) o[j] = f32x4{0.f, 0.f, 0.f, 0.f};
  const float* vbase = kvs + h_l * 49 * 32;
#pragma unroll
  for (int k = 0; k < 49; k++) {
    const f32x4* vr = (const f32x4*)(vbase + k * 32);
    float p = S[k];
#pragma unroll
    for (int j = 0; j < 8; j++) o[j] += p * vr[j];
  }
#pragma unroll
  for (int j = 0; j < 8; j++) o[j] *= inv;

  if (lane < 49) {
    unsigned short* op = y2 + mq * 256 + h * 32;
#pragma unroll
    for (int j2 = 0; j2 < 4; j2++) {
      us8 pk;
      pk[0] = f2bf(o[2 * j2].x); pk[1] = f2bf(o[2 * j2].y);
      pk[2] = f2bf(o[2 * j2].z); pk[3] = f2bf(o[2 * j2].w);
      pk[4] = f2bf(o[2 * j2 + 1].x); pk[5] = f2bf(o[2 * j2 + 1].y);
      pk[6] = f2bf(o[2 * j2 + 1].z); pk[7] = f2bf(o[2 * j2 + 1].w);
      *((us8*)(op + j2 * 8)) = pk;
    }
  }
}

// ---------------- depthwise 3x3 + bias + BN + GELU, row-sweep ----------------
// R13: branch-free inner loop (clamped pointers + zeroed weights for invalid
// rows), pointer-bump addressing, unroll-3 to kill rotation movs.
__global__ __launch_bounds__(256) void dwconv_kernel(
    const unsigned short* __restrict__ h1, const float* __restrict__ wT,
    const float* __restrict__ bias, const float* __restrict__ bng,
    const float* __restrict__ bnb, unsigned short* __restrict__ h2) {
  const int blk = blockIdx.x;
  const int q = blk & 3;
  const int y = (blk >> 2) % 112;
  const int b = blk / (4 * 112);
  const int tid = threadIdx.x;
  const int c0 = tid * 4;
  const int x0 = q * 28;

  f32x4 wv[9];
#pragma unroll
  for (int wi = 0; wi < 9; wi++) wv[wi] = *(const f32x4*)(wT + wi * HID_ + c0);

  const float bnrs = 0.9999950000374997f;
  f32x4 bv = ((const f32x4*)bias)[tid];
  f32x4 sc = ((const f32x4*)bng)[tid];
  sc *= bnrs;
  f32x4 sh = ((const f32x4*)bnb)[tid];
  sh += bv * sc;

  const unsigned short* rp[3];
#pragma unroll
  for (int r = 0; r < 3; r++) {
    int yy = y - 1 + r;
    if ((unsigned)yy >= 112u) {
      yy = y;
      wv[r * 3 + 0] = f32x4{0.f, 0.f, 0.f, 0.f};
      wv[r * 3 + 1] = f32x4{0.f, 0.f, 0.f, 0.f};
      wv[r * 3 + 2] = f32x4{0.f, 0.f, 0.f, 0.f};
    }
    rp[r] = h1 + ((size_t)b * HW_ + (size_t)yy * 112 + x0) * HID_ + c0;
  }

  auto ld = [&](const unsigned short* p) -> f32x4 {
    us4 v = *(const us4*)p;
    f32x4 f;
    f.x = bf2f(v.x); f.y = bf2f(v.y); f.z = bf2f(v.z); f.w = bf2f(v.w);
    return f;
  };

  f32x4 colP[3], colC[3], colN[3];
  if (x0 > 0) {
#pragma unroll
    for (int r = 0; r < 3; r++) colP[r] = ld(rp[r] - HID_);
  } else {
#pragma unroll
    for (int r = 0; r < 3; r++) colP[r] = f32x4{0.f, 0.f, 0.f, 0.f};
  }
#pragma unroll
  for (int r = 0; r < 3; r++) colC[r] = ld(rp[r]);

  unsigned short* outp = h2 + ((size_t)b * HW_ + (size_t)y * 112 + x0) * HID_ + c0;

  auto convemit = [&](unsigned short* op) {
    f32x4 a = {0.f, 0.f, 0.f, 0.f};
#pragma unroll
    for (int r = 0; r < 3; r++) {
      a += colP[r] * wv[r * 3 + 0];
      a += colC[r] * wv[r * 3 + 1];
      a += colN[r] * wv[r * 3 + 2];
    }
    a = a * sc + sh;
    us4 o;
    o.x = f2bf(gelu_f(a.x));
    o.y = f2bf(gelu_f(a.y));
    o.z = f2bf(gelu_f(a.z));
    o.w = f2bf(gelu_f(a.w));
    *(us4*)op = o;
  };

#pragma unroll 3
  for (int i = 0; i < 27; ++i) {
#pragma unroll
    for (int r = 0; r < 3; r++) colN[r] = ld(rp[r] + (size_t)(i + 1) * HID_);
    convemit(outp + (size_t)i * HID_);
#pragma unroll
    for (int r = 0; r < 3; r++) { colP[r] = colC[r]; colC[r] = colN[r]; }
  }
  if (x0 + 28 < 112) {
#pragma unroll
    for (int r = 0; r < 3; r++) colN[r] = ld(rp[r] + (size_t)28 * HID_);
  } else {
#pragma unroll
    for (int r = 0; r < 3; r++) colN[r] = f32x4{0.f, 0.f, 0.f, 0.f};
  }
  convemit(outp + (size_t)27 * HID_);
}

extern "C" void kernel_launch(void* const* d_in, const int* in_sizes, int n_in,
                              void* d_out, int out_size, void* d_ws, size_t ws_size,
                              hipStream_t stream) {
  const float* x      = (const float*)d_in[0];
  const float* ln1_g  = (const float*)d_in[1];
  const float* ln1_b  = (const float*)d_in[2];
  const float* qkv_w  = (const float*)d_in[3];
  const float* qkv_b  = (const float*)d_in[4];
  const float* rpe    = (const float*)d_in[5];
  const float* proj_w = (const float*)d_in[6];
  const float* proj_b = (const float*)d_in[7];
  const float* ln2_g  = (const float*)d_in[8];
  const float* ln2_b  = (const float*)d_in[9];
  const float* c1_w   = (const float*)d_in[10];
  const float* c1_b   = (const float*)d_in[11];
  const float* bn1_g  = (const float*)d_in[12];
  const float* bn1_b  = (const float*)d_in[13];
  const float* dw_w   = (const float*)d_in[14];
  const float* dw_b   = (const float*)d_in[15];
  const float* bn2_g  = (const float*)d_in[16];
  const float* bn2_b  = (const float*)d_in[17];
  const float* c3_w   = (const float*)d_in[18];
  const float* c3_b   = (const float*)d_in[19];
  const float* bn3_g  = (const float*)d_in[20];
  const float* bn3_b  = (const float*)d_in[21];

  // ---- workspace layout (liveness-aliased) ----
  char* ws = (char*)d_ws;
  size_t off = 0;
  float* t = (float*)(ws + off);                    off += (size_t)M_ * 256 * 4;
  unsigned short* S1 = (unsigned short*)(ws + off); off += (size_t)M_ * 1024 * 2;
  unsigned short* S2 = (unsigned short*)(ws + off); off += (size_t)M_ * 1024 * 2;
  unsigned short* yb = S2;  // alias: never live at the same time as S2
  unsigned short* wb_qkv  = (unsigned short*)(ws + off); off += (size_t)2 * 768 * 256 * 2;
  unsigned short* wb_proj = (unsigned short*)(ws + off); off += (size_t)2 * 256 * 256 * 2;
  unsigned short* wb_c1   = (unsigned short*)(ws + off); off += (size_t)2 * 1024 * 256 * 2;
  unsigned short* wb_c3   = (unsigned short*)(ws + off); off += (size_t)2 * 256 * 1024 * 2;
  float* wT = (float*)(ws + off);                   off += (size_t)2 * HID_ * 9 * 4;
  if (off > ws_size) return;  // clean failure instead of OOB crash

  // weight prep
  cast_bf16_kernel<<<384, 256, 0, stream>>>(qkv_w, wb_qkv, 2 * 768 * 256 / 4);
  cast_bf16_kernel<<<128, 256, 0, stream>>>(proj_w, wb_proj, 2 * 256 * 256 / 4);
  cast_bf16_kernel<<<512, 256, 0, stream>>>(c1_w, wb_c1, 2 * 1024 * 256 / 4);
  cast_bf16_kernel<<<512, 256, 0, stream>>>(c3_w, wb_c3, 2 * 256 * 1024 / 4);
  dwT_kernel<<<72, 256, 0, stream>>>(dw_w, wT);

  transpose_in_kernel<<<dim3(392, 8, 4), dim3(32, 8), 0, stream>>>(x, t);

  for (int i = 0; i < 2; i++) {
    ln_kernel<<<M_ / 4, 256, 0, stream>>>(t, ln1_g + i * 256, ln1_b + i * 256, yb);
    gemm_kernel<0><<<dim3(6, 392), 256, 0, stream>>>(
        yb, wb_qkv + (size_t)i * 768 * 256, qkv_b + i * 768, nullptr, nullptr,
        nullptr, S1, 768, 256);
    attn_kernel<<<2048, 256, 0, stream>>>(S1, rpe + (size_t)i * 169 * 8, yb);
    gemm_kernel<1><<<dim3(2, 392), 256, 0, stream>>>(
        yb, wb_proj + (size_t)i * 256 * 256, proj_b + i * 256, nullptr, nullptr,
        t, nullptr, 256, 256);
    ln_kernel<<<M_ / 4, 256, 0, stream>>>(t, ln2_g + i * 256, ln2_b + i * 256, yb);
    gemm_kernel<2><<<dim3(8, 392), 256, 0, stream>>>(
        yb, wb_c1 + (size_t)i * 1024 * 256, c1_b + i * 1024, bn1_g + i * 1024,
        bn1_b + i * 1024, nullptr, S1, 1024, 256);
    dwconv_kernel<<<4 * 112 * 4, 256, 0, stream>>>(S1, wT + (size_t)i * HID_ * 9,
                                                   dw_b + i * 1024, bn2_g + i * 1024,
                                                   bn2_b + i * 1024, S2);
    gemm_kernel<3><<<dim3(2, 392), 256, 0, stream>>>(
        S2, wb_c3 + (size_t)i * 256 * 1024, c3_b + i * 256, bn3_g + i * 256,
        bn3_b + i * 256, t, nullptr, 256, 1024);
  }

  transpose_out_kernel<<<dim3(392, 8, 4), dim3(32, 8), 0, stream>>>(t, (float*)d_out);
}

// Round 16
// 755.949 us; speedup vs baseline: 6.5467x; 6.5467x over previous
//
#include <hip/hip_runtime.h>

typedef __attribute__((ext_vector_type(4))) float f32x4;
typedef __attribute__((ext_vector_type(8))) __bf16 bf16x8;
typedef __attribute__((ext_vector_type(4))) unsigned short us4;
typedef __attribute__((ext_vector_type(8))) unsigned short us8;

#define DEVI static __device__ __forceinline__

constexpr int C_   = 256;
constexpr int HW_  = 112 * 112;   // 12544
constexpr int M_   = 4 * HW_;     // 50176 tokens
constexpr int HID_ = 1024;

DEVI unsigned short f2bf(float f) {
  unsigned u = __float_as_uint(f);
  u += 0x7fffu + ((u >> 16) & 1u);
  return (unsigned short)(u >> 16);
}
DEVI float bf2f(unsigned short s) { return __uint_as_float(((unsigned)s) << 16); }
// tanh-form GELU via v_exp_f32 (~9 VALU vs ~25 for erff); max dev ~3e-4
DEVI float gelu_f(float x) {
  float u = x * (0.7978845608028654f + 0.0356774081363001f * x * x);
  float e = __expf(2.f * u);
  float t = 1.f - 2.f / (e + 1.f);
  return 0.5f * x * (1.f + t);
}

// ---------------- fp32 -> bf16 cast (weights) ----------------
__global__ void cast_bf16_kernel(const float* __restrict__ src,
                                 unsigned short* __restrict__ dst, int n4) {
  int i = blockIdx.x * 256 + threadIdx.x;
  if (i < n4) {
    f32x4 v = ((const f32x4*)src)[i];
    us4 o;
    o.x = f2bf(v.x); o.y = f2bf(v.y); o.z = f2bf(v.z); o.w = f2bf(v.w);
    ((us4*)dst)[i] = o;
  }
}

// ---------------- dw weights (blk, c, 9) -> (blk, 9, c) ----------------
__global__ void dwT_kernel(const float* __restrict__ w, float* __restrict__ wT) {
  int i = blockIdx.x * 256 + threadIdx.x;
  if (i < 2 * HID_ * 9) {
    int blkI = i / (HID_ * 9), rem = i % (HID_ * 9);
    int c = rem / 9, wi = rem % 9;
    wT[blkI * HID_ * 9 + wi * HID_ + c] = w[i];
  }
}

// ---------------- (B,C,HW) -> (B,HW,C) ----------------
__global__ void transpose_in_kernel(const float* __restrict__ x, float* __restrict__ t) {
  __shared__ float tile[32][33];
  int b = blockIdx.z;
  int p0 = blockIdx.x * 32, c0 = blockIdx.y * 32;
  int tx = threadIdx.x, ty = threadIdx.y;
  const float* xb = x + (size_t)b * C_ * HW_;
#pragma unroll
  for (int i = 0; i < 4; i++)
    tile[ty + 8 * i][tx] = xb[(size_t)(c0 + ty + 8 * i) * HW_ + p0 + tx];
  __syncthreads();
  float* tb = t + (size_t)b * HW_ * C_;
#pragma unroll
  for (int i = 0; i < 4; i++)
    tb[(size_t)(p0 + ty + 8 * i) * C_ + c0 + tx] = tile[tx][ty + 8 * i];
}

// ---------------- (B,HW,C) -> (B,C,HW) ----------------
__global__ void transpose_out_kernel(const float* __restrict__ t, float* __restrict__ out) {
  __shared__ float tile[32][33];
  int b = blockIdx.z;
  int p0 = blockIdx.x * 32, c0 = blockIdx.y * 32;
  int tx = threadIdx.x, ty = threadIdx.y;
  const float* tb = t + (size_t)b * HW_ * C_;
#pragma unroll
  for (int i = 0; i < 4; i++)
    tile[ty + 8 * i][tx] = tb[(size_t)(p0 + ty + 8 * i) * C_ + c0 + tx];
  __syncthreads();
  float* ob = out + (size_t)b * C_ * HW_;
#pragma unroll
  for (int i = 0; i < 4; i++)
    ob[(size_t)(c0 + ty + 8 * i) * HW_ + p0 + tx] = tile[tx][ty + 8 * i];
}

// ---------------- LayerNorm (fp32 in, bf16 out), one wave per row ----------------
__global__ void ln_kernel(const float* __restrict__ t, const float* __restrict__ g,
                          const float* __restrict__ bsh, unsigned short* __restrict__ out) {
  int row = blockIdx.x * 4 + (threadIdx.x >> 6);
  int lane = threadIdx.x & 63;
  const float* tr = t + (size_t)row * C_;
  f32x4 v = ((const f32x4*)tr)[lane];
  float s  = v.x + v.y + v.z + v.w;
  float s2 = v.x * v.x + v.y * v.y + v.z * v.z + v.w * v.w;
#pragma unroll
  for (int off = 1; off < 64; off <<= 1) {
    s  += __shfl_xor(s, off);
    s2 += __shfl_xor(s2, off);
  }
  float mean = s * (1.f / 256.f);
  float var  = s2 * (1.f / 256.f) - mean * mean;
  float rstd = rsqrtf(var + 1e-6f);
  f32x4 gg = ((const f32x4*)g)[lane];
  f32x4 bb = ((const f32x4*)bsh)[lane];
  us4 o;
  o.x = f2bf((v.x - mean) * rstd * gg.x + bb.x);
  o.y = f2bf((v.y - mean) * rstd * gg.y + bb.y);
  o.z = f2bf((v.z - mean) * rstd * gg.z + bb.z);
  o.w = f2bf((v.w - mean) * rstd * gg.w + bb.w);
  ((us4*)(out + (size_t)row * C_))[lane] = o;
}

// ---------------- GEMM: out(M,N) = A(M,K) * Wt(N,K)^T, bf16 in, fp32 acc ----------------
// 128x128 block tile, 4 waves (2x2, 64x64 each), 3 LDS buffers (48KB -> 3 blocks/CU),
// depth-2 prefetch, counted vmcnt(4). XCD-chunked swizzle for A-panel L2 reuse.
// bf16 epilogues (EPI 0/2) staged through LDS -> 16B/lane coalesced stores.
template <int EPI>
__global__ __launch_bounds__(256, 2) void gemm_kernel(
    const unsigned short* __restrict__ A, const unsigned short* __restrict__ Wt,
    const float* __restrict__ bias, const float* __restrict__ bng,
    const float* __restrict__ bnb, float* __restrict__ resid,
    unsigned short* __restrict__ outb, int N, int K) {
  // per buffer: A[128*32] shorts @0, B[128*32] shorts @4096; 8192 shorts = 16KB
  __shared__ unsigned short smem[3 * 8192];
  const int tid = threadIdx.x;
  const int wave = tid >> 6, lane = tid & 63;

  // XCD-chunked swizzle (all grids have nwg % 8 == 0); bn is the fast dim so
  // one XCD owns all bn-blocks of a run of bm -> A-panel fetched once per XCD.
  const int bnN = gridDim.x;
  const int nwg = bnN * gridDim.y;
  int wg = blockIdx.y * bnN + blockIdx.x;
  const int chunk = nwg >> 3;
  wg = (wg & 7) * chunk + (wg >> 3);
  const int bn = wg % bnN;
  const int bm = wg / bnN;

  const int wm = wave >> 1, wn = wave & 1;
  const int laneRow = lane >> 2;      // 0..15
  const int scol = (lane & 3) * 8;    // shorts (16B per lane)
  const size_t aBase = (size_t)bm * 128;
  const size_t bBase = (size_t)bn * 128;

  f32x4 acc[4][4];
#pragma unroll
  for (int i = 0; i < 4; i++)
#pragma unroll
    for (int j = 0; j < 4; j++) acc[i][j] = f32x4{0.f, 0.f, 0.f, 0.f};

  // 4 global_load_lds per wave per step (2 for A's 32 rows, 2 for B's 32 rows)
  auto stage = [&](int buf, int kt) {
    const int k0 = kt << 5;
    unsigned short* sb = smem + buf * 8192;
#pragma unroll
    for (int r = 0; r < 2; ++r) {
      int row = wave * 32 + r * 16 + laneRow;
      __builtin_amdgcn_global_load_lds(
          (const __attribute__((address_space(1))) void*)(A + (aBase + row) * K + k0 + scol),
          (__attribute__((address_space(3))) void*)(sb + row * 32 + scol), 16, 0, 0);
    }
#pragma unroll
    for (int r = 0; r < 2; ++r) {
      int row = wave * 32 + r * 16 + laneRow;
      __builtin_amdgcn_global_load_lds(
          (const __attribute__((address_space(1))) void*)(Wt + (bBase + row) * K + k0 + scol),
          (__attribute__((address_space(3))) void*)(sb + 4096 + row * 32 + scol), 16, 0, 0);
    }
  };

  const int nK = K >> 5;
  stage(0, 0);
  if (nK > 1) {
    stage(1, 1);
    asm volatile("s_waitcnt vmcnt(4)" ::: "memory");
  } else {
    asm volatile("s_waitcnt vmcnt(0)" ::: "memory");
  }
  __builtin_amdgcn_s_barrier();
  asm volatile("" ::: "memory");

  const int fr = lane & 15, kh = (lane >> 4) * 8;
  for (int kt = 0; kt < nK; ++kt) {
    const int cur = kt % 3;
    const bool more2 = (kt + 2 < nK);
    if (more2) stage((kt + 2) % 3, kt + 2);  // depth-2 prefetch flies over compute

    const unsigned short* sb = smem + cur * 8192;
    bf16x8 af[4], bfr[4];
#pragma unroll
    for (int mi = 0; mi < 4; mi++)
      af[mi] = *(const bf16x8*)(sb + (wm * 64 + mi * 16 + fr) * 32 + kh);
#pragma unroll
    for (int ni = 0; ni < 4; ni++)
      bfr[ni] = *(const bf16x8*)(sb + 4096 + (wn * 64 + ni * 16 + fr) * 32 + kh);
#pragma unroll
    for (int mi = 0; mi < 4; mi++)
#pragma unroll
      for (int ni = 0; ni < 4; ni++)
        acc[mi][ni] = __builtin_amdgcn_mfma_f32_16x16x32_bf16(af[mi], bfr[ni], acc[mi][ni], 0, 0, 0);

    if (kt + 1 < nK) {
      if (more2) {
        asm volatile("s_waitcnt vmcnt(4)" ::: "memory");  // retire tile kt+1 only
      } else {
        asm volatile("s_waitcnt vmcnt(0)" ::: "memory");  // boundary drain (once)
      }
      __builtin_amdgcn_s_barrier();
      asm volatile("" ::: "memory");
    }
  }

  const int r4 = (lane >> 4) * 4;
  const float bnrs = 0.9999950000374997f;  // rsqrt(1 + 1e-5)

  if (EPI == 0 || EPI == 2) {
    // --- staged bf16 epilogue: LDS tile [128][128] shorts with row-XOR swizzle ---
    __syncthreads();  // all waves done reading K-loop smem
    unsigned short* esm = smem;  // 16384 shorts = 32KB <= 48KB
#pragma unroll
    for (int ni = 0; ni < 4; ni++) {
      int cl = wn * 64 + ni * 16 + fr;       // local col 0..127
      int cg = bn * 128 + cl;                // global col
      float bval = bias[cg];
      float sc = 0.f, sh = 0.f;
      if (EPI == 2) { sc = bng[cg] * bnrs; sh = bnb[cg]; }
#pragma unroll
      for (int mi = 0; mi < 4; mi++) {
#pragma unroll
        for (int j = 0; j < 4; j++) {
          int row = wm * 64 + mi * 16 + r4 + j;
          float v = acc[mi][ni][j] + bval;
          if (EPI == 2) v = gelu_f(v * sc + sh);
          esm[row * 128 + (cl ^ (((row >> 2) & 3) << 4))] = f2bf(v);
        }
      }
    }
    __syncthreads();
#pragma unroll
    for (int it = 0; it < 8; it++) {
      int idx = it * 256 + tid;
      int row = idx >> 4;
      int c0 = (idx & 15) * 8;
      int c0s = c0 ^ (((row >> 2) & 3) << 4);
      us8 v = *(const us8*)(esm + row * 128 + c0s);
      *(us8*)(outb + (aBase + row) * (size_t)N + bn * 128 + c0) = v;
    }
  } else {
    // --- fp32 residual RMW (already 64B-coalesced) ---
#pragma unroll
    for (int ni = 0; ni < 4; ni++) {
      int cg = bn * 128 + wn * 64 + ni * 16 + fr;
      float bval = bias[cg];
      float sc = 0.f, sh = 0.f;
      if (EPI == 3) { sc = bng[cg] * bnrs; sh = bnb[cg]; }
#pragma unroll
      for (int mi = 0; mi < 4; mi++) {
#pragma unroll
        for (int j = 0; j < 4; j++) {
          size_t rg = aBase + wm * 64 + mi * 16 + r4 + j;
          float v = acc[mi][ni][j] + bval;
          if (EPI == 1) {
            resid[rg * 256 + cg] += v;
          } else {
            resid[rg * 256 + cg] += gelu_f(v * sc + sh);
          }
        }
      }
    }
  }
}

// ---------------- windowed attention, register-resident (R13-proven, reverted) ----------------
// K,V f32 in LDS (25KB+25KB); rpe staged for ONLY this block's 4 heads (2.7KB)
// -> 51.7KB LDS -> 3 blocks/CU. VGPR 76, no spill (R13-verified, 78.7us).
// R9/R10/R14 lesson: ANY restructure adding concurrent live state (bf16-V unpack,
// o32[32], V-stage while S[49] live) spills -> 0.6-2.1ms. Do not touch.
__global__ __launch_bounds__(256, 2) void attn_kernel(const unsigned short* __restrict__ qkv,
                                                      const float* __restrict__ rpe,
                                                      unsigned short* __restrict__ y2) {
  __shared__ float ks[4 * 49 * 32];
  __shared__ float vs[4 * 49 * 32];
  __shared__ float rpet[4 * 169];  // [h_l][ridx]
  const int tid = threadIdx.x;
  const int blk = blockIdx.x;
  const int win = blk >> 1;
  const int hg = (blk & 1) * 4;
  const int b = win >> 8, rem = win & 255;
  const int ph = rem >> 4, pw = rem & 15;
  const size_t base = (size_t)b * HW_ + ph * 7 * 112 + pw * 7;

  for (int c = tid; c < 169 * 4; c += 256)
    rpet[(c & 3) * 169 + (c >> 2)] = rpe[(c >> 2) * 8 + hg + (c & 3)];
  for (int c = tid; c < 4 * 49 * 8; c += 256) {
    int h_l = c / (49 * 8);
    int r2 = c - h_l * (49 * 8);
    int tok = r2 >> 3, ch4 = r2 & 7;
    size_t m = base + (tok / 7) * 112 + (tok % 7);
    const unsigned short* kp = qkv + m * 768 + 256 + (hg + h_l) * 32 + ch4 * 4;
    us4 kv = *(const us4*)kp;
    us4 vv = *(const us4*)(kp + 256);
    float* kd = ks + (h_l * 49 + tok) * 32 + ch4 * 4;
    float* vd = vs + (h_l * 49 + tok) * 32 + ch4 * 4;
    kd[0] = bf2f(kv.x); kd[1] = bf2f(kv.y); kd[2] = bf2f(kv.z); kd[3] = bf2f(kv.w);
    vd[0] = bf2f(vv.x); vd[1] = bf2f(vv.y); vd[2] = bf2f(vv.z); vd[3] = bf2f(vv.w);
  }

  const int lane = tid & 63;
  const int h_l = tid >> 6;
  const int h = hg + h_l;
  const int qi = lane < 49 ? lane : 48;
  const size_t mq = base + (qi / 7) * 112 + (qi % 7);

  f32x4 q[8];
  {
    const unsigned short* qp = qkv + mq * 768 + h * 32;
    const float qsc = 0.17677669529663689f;  // 1/sqrt(32)
#pragma unroll
    for (int j = 0; j < 8; j++) {
      us4 v = *(const us4*)(qp + j * 4);
      q[j].x = bf2f(v.x) * qsc; q[j].y = bf2f(v.y) * qsc;
      q[j].z = bf2f(v.z) * qsc; q[j].w = bf2f(v.w) * qsc;
    }
  }
  __syncthreads();

  float S[49];
  const float* kbase = ks + h_l * 49 * 32;
#pragma unroll
  for (int ki = 0; ki < 49; ki++) {
    const f32x4* kr = (const f32x4*)(kbase + ki * 32);
    f32x4 a0 = {0.f, 0.f, 0.f, 0.f}, a1 = {0.f, 0.f, 0.f, 0.f};
#pragma unroll
    for (int j = 0; j < 4; j++) {
      a0 += q[2 * j] * kr[2 * j];
      a1 += q[2 * j + 1] * kr[2 * j + 1];
    }
    f32x4 as = a0 + a1;
    S[ki] = (as.x + as.z) + (as.y + as.w);
  }

  const int qr = qi / 7, qc = qi % 7;
  const float* rp = rpet + h_l * 169;
#pragma unroll
  for (int ki = 0; ki < 49; ki++) {
    int ridx = (qr - ki / 7 + 6) * 13 + (qc - ki % 7 + 6);
    S[ki] += rp[ridx];
  }
  float mx = S[0];
#pragma unroll
  for (int ki = 1; ki < 49; ki++) mx = fmaxf(mx, S[ki]);
  float sum = 0.f;
#pragma unroll
  for (int ki = 0; ki < 49; ki++) {
    float e = __expf(S[ki] - mx);
    S[ki] = e;
    sum += e;
  }
  float inv = 1.f / sum;

  f32x4 o[8];
#pragma unroll
  for (int j = 0; j < 8; j++) o[j] = f32x4{0.f, 0.f, 0.f, 0.f};
  const float* vbase = vs + h_l * 49 * 32;
#pragma unroll
  for (int k = 0; k < 49; k++) {
    const f32x4* vr = (const f32x4*)(vbase + k * 32);
    float p = S[k];
#pragma unroll
    for (int j = 0; j < 8; j++) o[j] += p * vr[j];
  }
#pragma unroll
  for (int j = 0; j < 8; j++) o[j] *= inv;

  if (lane < 49) {
    unsigned short* op = y2 + mq * 256 + h * 32;
#pragma unroll
    for (int j2 = 0; j2 < 4; j2++) {
      us8 pk;
      pk[0] = f2bf(o[2 * j2].x); pk[1] = f2bf(o[2 * j2].y);
      pk[2] = f2bf(o[2 * j2].z); pk[3] = f2bf(o[2 * j2].w);
      pk[4] = f2bf(o[2 * j2 + 1].x); pk[5] = f2bf(o[2 * j2 + 1].y);
      pk[6] = f2bf(o[2 * j2 + 1].z); pk[7] = f2bf(o[2 * j2 + 1].w);
      *((us8*)(op + j2 * 8)) = pk;
    }
  }
}

// ---------------- depthwise 3x3 + bias + BN + GELU, row-sweep ----------------
// R13: branch-free inner loop (clamped pointers + zeroed weights for invalid
// rows), pointer-bump addressing, unroll-3 to kill rotation movs.
__global__ __launch_bounds__(256) void dwconv_kernel(
    const unsigned short* __restrict__ h1, const float* __restrict__ wT,
    const float* __restrict__ bias, const float* __restrict__ bng,
    const float* __restrict__ bnb, unsigned short* __restrict__ h2) {
  const int blk = blockIdx.x;
  const int q = blk & 3;
  const int y = (blk >> 2) % 112;
  const int b = blk / (4 * 112);
  const int tid = threadIdx.x;
  const int c0 = tid * 4;
  const int x0 = q * 28;

  f32x4 wv[9];
#pragma unroll
  for (int wi = 0; wi < 9; wi++) wv[wi] = *(const f32x4*)(wT + wi * HID_ + c0);

  const float bnrs = 0.9999950000374997f;
  f32x4 bv = ((const f32x4*)bias)[tid];
  f32x4 sc = ((const f32x4*)bng)[tid];
  sc *= bnrs;
  f32x4 sh = ((const f32x4*)bnb)[tid];
  sh += bv * sc;

  const unsigned short* rp[3];
#pragma unroll
  for (int r = 0; r < 3; r++) {
    int yy = y - 1 + r;
    if ((unsigned)yy >= 112u) {
      yy = y;
      wv[r * 3 + 0] = f32x4{0.f, 0.f, 0.f, 0.f};
      wv[r * 3 + 1] = f32x4{0.f, 0.f, 0.f, 0.f};
      wv[r * 3 + 2] = f32x4{0.f, 0.f, 0.f, 0.f};
    }
    rp[r] = h1 + ((size_t)b * HW_ + (size_t)yy * 112 + x0) * HID_ + c0;
  }

  auto ld = [&](const unsigned short* p) -> f32x4 {
    us4 v = *(const us4*)p;
    f32x4 f;
    f.x = bf2f(v.x); f.y = bf2f(v.y); f.z = bf2f(v.z); f.w = bf2f(v.w);
    return f;
  };

  f32x4 colP[3], colC[3], colN[3];
  if (x0 > 0) {
#pragma unroll
    for (int r = 0; r < 3; r++) colP[r] = ld(rp[r] - HID_);
  } else {
#pragma unroll
    for (int r = 0; r < 3; r++) colP[r] = f32x4{0.f, 0.f, 0.f, 0.f};
  }
#pragma unroll
  for (int r = 0; r < 3; r++) colC[r] = ld(rp[r]);

  unsigned short* outp = h2 + ((size_t)b * HW_ + (size_t)y * 112 + x0) * HID_ + c0;

  auto convemit = [&](unsigned short* op) {
    f32x4 a = {0.f, 0.f, 0.f, 0.f};
#pragma unroll
    for (int r = 0; r < 3; r++) {
      a += colP[r] * wv[r * 3 + 0];
      a += colC[r] * wv[r * 3 + 1];
      a += colN[r] * wv[r * 3 + 2];
    }
    a = a * sc + sh;
    us4 o;
    o.x = f2bf(gelu_f(a.x));
    o.y = f2bf(gelu_f(a.y));
    o.z = f2bf(gelu_f(a.z));
    o.w = f2bf(gelu_f(a.w));
    *(us4*)op = o;
  };

#pragma unroll 3
  for (int i = 0; i < 27; ++i) {
#pragma unroll
    for (int r = 0; r < 3; r++) colN[r] = ld(rp[r] + (size_t)(i + 1) * HID_);
    convemit(outp + (size_t)i * HID_);
#pragma unroll
    for (int r = 0; r < 3; r++) { colP[r] = colC[r]; colC[r] = colN[r]; }
  }
  if (x0 + 28 < 112) {
#pragma unroll
    for (int r = 0; r < 3; r++) colN[r] = ld(rp[r] + (size_t)28 * HID_);
  } else {
#pragma unroll
    for (int r = 0; r < 3; r++) colN[r] = f32x4{0.f, 0.f, 0.f, 0.f};
  }
  convemit(outp + (size_t)27 * HID_);
}

extern "C" void kernel_launch(void* const* d_in, const int* in_sizes, int n_in,
                              void* d_out, int out_size, void* d_ws, size_t ws_size,
                              hipStream_t stream) {
  const float* x      = (const float*)d_in[0];
  const float* ln1_g  = (const float*)d_in[1];
  const float* ln1_b  = (const float*)d_in[2];
  const float* qkv_w  = (const float*)d_in[3];
  const float* qkv_b  = (const float*)d_in[4];
  const float* rpe    = (const float*)d_in[5];
  const float* proj_w = (const float*)d_in[6];
  const float* proj_b = (const float*)d_in[7];
  const float* ln2_g  = (const float*)d_in[8];
  const float* ln2_b  = (const float*)d_in[9];
  const float* c1_w   = (const float*)d_in[10];
  const float* c1_b   = (const float*)d_in[11];
  const float* bn1_g  = (const float*)d_in[12];
  const float* bn1_b  = (const float*)d_in[13];
  const float* dw_w   = (const float*)d_in[14];
  const float* dw_b   = (const float*)d_in[15];
  const float* bn2_g  = (const float*)d_in[16];
  const float* bn2_b  = (const float*)d_in[17];
  const float* c3_w   = (const float*)d_in[18];
  const float* c3_b   = (const float*)d_in[19];
  const float* bn3_g  = (const float*)d_in[20];
  const float* bn3_b  = (const float*)d_in[21];

  // ---- workspace layout (liveness-aliased) ----
  char* ws = (char*)d_ws;
  size_t off = 0;
  float* t = (float*)(ws + off);                    off += (size_t)M_ * 256 * 4;
  unsigned short* S1 = (unsigned short*)(ws + off); off += (size_t)M_ * 1024 * 2;
  unsigned short* S2 = (unsigned short*)(ws + off); off += (size_t)M_ * 1024 * 2;
  unsigned short* yb = S2;  // alias: never live at the same time as S2
  unsigned short* wb_qkv  = (unsigned short*)(ws + off); off += (size_t)2 * 768 * 256 * 2;
  unsigned short* wb_proj = (unsigned short*)(ws + off); off += (size_t)2 * 256 * 256 * 2;
  unsigned short* wb_c1   = (unsigned short*)(ws + off); off += (size_t)2 * 1024 * 256 * 2;
  unsigned short* wb_c3   = (unsigned short*)(ws + off); off += (size_t)2 * 256 * 1024 * 2;
  float* wT = (float*)(ws + off);                   off += (size_t)2 * HID_ * 9 * 4;
  if (off > ws_size) return;  // clean failure instead of OOB crash

  // weight prep
  cast_bf16_kernel<<<384, 256, 0, stream>>>(qkv_w, wb_qkv, 2 * 768 * 256 / 4);
  cast_bf16_kernel<<<128, 256, 0, stream>>>(proj_w, wb_proj, 2 * 256 * 256 / 4);
  cast_bf16_kernel<<<512, 256, 0, stream>>>(c1_w, wb_c1, 2 * 1024 * 256 / 4);
  cast_bf16_kernel<<<512, 256, 0, stream>>>(c3_w, wb_c3, 2 * 256 * 1024 / 4);
  dwT_kernel<<<72, 256, 0, stream>>>(dw_w, wT);

  transpose_in_kernel<<<dim3(392, 8, 4), dim3(32, 8), 0, stream>>>(x, t);

  for (int i = 0; i < 2; i++) {
    ln_kernel<<<M_ / 4, 256, 0, stream>>>(t, ln1_g + i * 256, ln1_b + i * 256, yb);
    gemm_kernel<0><<<dim3(6, 392), 256, 0, stream>>>(
        yb, wb_qkv + (size_t)i * 768 * 256, qkv_b + i * 768, nullptr, nullptr,
        nullptr, S1, 768, 256);
    attn_kernel<<<2048, 256, 0, stream>>>(S1, rpe + (size_t)i * 169 * 8, yb);
    gemm_kernel<1><<<dim3(2, 392), 256, 0, stream>>>(
        yb, wb_proj + (size_t)i * 256 * 256, proj_b + i * 256, nullptr, nullptr,
        t, nullptr, 256, 256);
    ln_kernel<<<M_ / 4, 256, 0, stream>>>(t, ln2_g + i * 256, ln2_b + i * 256, yb);
    gemm_kernel<2><<<dim3(8, 392), 256, 0, stream>>>(
        yb, wb_c1 + (size_t)i * 1024 * 256, c1_b + i * 1024, bn1_g + i * 1024,
        bn1_b + i * 1024, nullptr, S1, 1024, 256);
    dwconv_kernel<<<4 * 112 * 4, 256, 0, stream>>>(S1, wT + (size_t)i * HID_ * 9,
                                                   dw_b + i * 1024, bn2_g + i * 1024,
                                                   bn2_b + i * 1024, S2);
    gemm_kernel<3><<<dim3(2, 392), 256, 0, stream>>>(
        S2, wb_c3 + (size_t)i * 256 * 1024, c3_b + i * 256, bn3_g + i * 256,
        bn3_b + i * 256, t, nullptr, 256, 1024);
  }

  transpose_out_kernel<<<dim3(392, 8, 4), dim3(32, 8), 0, stream>>>(t, (float*)d_out);
}

// Round 17
// 686.540 us; speedup vs baseline: 7.2085x; 1.1011x over previous
//
#include <hip/hip_runtime.h>

typedef __attribute__((ext_vector_type(4))) float f32x4;
typedef __attribute__((ext_vector_type(8))) __bf16 bf16x8;
typedef __attribute__((ext_vector_type(4))) unsigned short us4;
typedef __attribute__((ext_vector_type(8))) unsigned short us8;

#define DEVI static __device__ __forceinline__

constexpr int C_   = 256;
constexpr int HW_  = 112 * 112;   // 12544
constexpr int M_   = 4 * HW_;     // 50176 tokens
constexpr int HID_ = 1024;

DEVI unsigned short f2bf(float f) {
  unsigned u = __float_as_uint(f);
  u += 0x7fffu + ((u >> 16) & 1u);
  return (unsigned short)(u >> 16);
}
DEVI float bf2f(unsigned short s) { return __uint_as_float(((unsigned)s) << 16); }
// tanh-form GELU via v_exp_f32 (~9 VALU vs ~25 for erff); max dev ~3e-4
DEVI float gelu_f(float x) {
  float u = x * (0.7978845608028654f + 0.0356774081363001f * x * x);
  float e = __expf(2.f * u);
  float t = 1.f - 2.f / (e + 1.f);
  return 0.5f * x * (1.f + t);
}

// ---------------- fp32 -> bf16 cast (weights) ----------------
__global__ void cast_bf16_kernel(const float* __restrict__ src,
                                 unsigned short* __restrict__ dst, int n4) {
  int i = blockIdx.x * 256 + threadIdx.x;
  if (i < n4) {
    f32x4 v = ((const f32x4*)src)[i];
    us4 o;
    o.x = f2bf(v.x); o.y = f2bf(v.y); o.z = f2bf(v.z); o.w = f2bf(v.w);
    ((us4*)dst)[i] = o;
  }
}

// ---------------- dw weights (blk, c, 9) -> (blk, 9, c) ----------------
__global__ void dwT_kernel(const float* __restrict__ w, float* __restrict__ wT) {
  int i = blockIdx.x * 256 + threadIdx.x;
  if (i < 2 * HID_ * 9) {
    int blkI = i / (HID_ * 9), rem = i % (HID_ * 9);
    int c = rem / 9, wi = rem % 9;
    wT[blkI * HID_ * 9 + wi * HID_ + c] = w[i];
  }
}

// ---------------- (B,C,HW) fp32 -> (B,HW,C) bf16 residual ----------------
__global__ void transpose_in_kernel(const float* __restrict__ x,
                                    unsigned short* __restrict__ t) {
  __shared__ float tile[32][33];
  int b = blockIdx.z;
  int p0 = blockIdx.x * 32, c0 = blockIdx.y * 32;
  int tx = threadIdx.x, ty = threadIdx.y;
  const float* xb = x + (size_t)b * C_ * HW_;
#pragma unroll
  for (int i = 0; i < 4; i++)
    tile[ty + 8 * i][tx] = xb[(size_t)(c0 + ty + 8 * i) * HW_ + p0 + tx];
  __syncthreads();
  unsigned short* tb = t + (size_t)b * HW_ * C_;
#pragma unroll
  for (int i = 0; i < 4; i++)
    tb[(size_t)(p0 + ty + 8 * i) * C_ + c0 + tx] = f2bf(tile[tx][ty + 8 * i]);
}

// ---------------- (B,HW,C) bf16 -> (B,C,HW) fp32 output ----------------
__global__ void transpose_out_kernel(const unsigned short* __restrict__ t,
                                     float* __restrict__ out) {
  __shared__ float tile[32][33];
  int b = blockIdx.z;
  int p0 = blockIdx.x * 32, c0 = blockIdx.y * 32;
  int tx = threadIdx.x, ty = threadIdx.y;
  const unsigned short* tb = t + (size_t)b * HW_ * C_;
#pragma unroll
  for (int i = 0; i < 4; i++)
    tile[ty + 8 * i][tx] = bf2f(tb[(size_t)(p0 + ty + 8 * i) * C_ + c0 + tx]);
  __syncthreads();
  float* ob = out + (size_t)b * C_ * HW_;
#pragma unroll
  for (int i = 0; i < 4; i++)
    ob[(size_t)(c0 + ty + 8 * i) * HW_ + p0 + tx] = tile[tx][ty + 8 * i];
}

// ---------------- LayerNorm (bf16 in, bf16 out), one wave per row ----------------
__global__ void ln_kernel(const unsigned short* __restrict__ t, const float* __restrict__ g,
                          const float* __restrict__ bsh, unsigned short* __restrict__ out) {
  int row = blockIdx.x * 4 + (threadIdx.x >> 6);
  int lane = threadIdx.x & 63;
  const unsigned short* tr = t + (size_t)row * C_;
  us4 v4 = ((const us4*)tr)[lane];
  f32x4 v;
  v.x = bf2f(v4.x); v.y = bf2f(v4.y); v.z = bf2f(v4.z); v.w = bf2f(v4.w);
  float s  = v.x + v.y + v.z + v.w;
  float s2 = v.x * v.x + v.y * v.y + v.z * v.z + v.w * v.w;
#pragma unroll
  for (int off = 1; off < 64; off <<= 1) {
    s  += __shfl_xor(s, off);
    s2 += __shfl_xor(s2, off);
  }
  float mean = s * (1.f / 256.f);
  float var  = s2 * (1.f / 256.f) - mean * mean;
  float rstd = rsqrtf(var + 1e-6f);
  f32x4 gg = ((const f32x4*)g)[lane];
  f32x4 bb = ((const f32x4*)bsh)[lane];
  us4 o;
  o.x = f2bf((v.x - mean) * rstd * gg.x + bb.x);
  o.y = f2bf((v.y - mean) * rstd * gg.y + bb.y);
  o.z = f2bf((v.z - mean) * rstd * gg.z + bb.z);
  o.w = f2bf((v.w - mean) * rstd * gg.w + bb.w);
  ((us4*)(out + (size_t)row * C_))[lane] = o;
}

// ---------------- GEMM: out(M,N) = A(M,K) * Wt(N,K)^T, bf16 in, fp32 acc ----------------
// 128x128 block tile, 4 waves (2x2, 64x64 each), 3 LDS buffers (48KB -> 3 blocks/CU),
// depth-2 prefetch, counted vmcnt(4). XCD-chunked swizzle for A-panel L2 reuse.
// ALL epilogues staged through LDS -> 16B/lane coalesced I/O.
// EPI 0: outb = acc+bias   EPI 1: resid(bf16) += acc+bias (RMW in writeout)
// EPI 2: outb = gelu(bn)   EPI 3: resid(bf16) += gelu(bn) (RMW in writeout)
template <int EPI>
__global__ __launch_bounds__(256, 2) void gemm_kernel(
    const unsigned short* __restrict__ A, const unsigned short* __restrict__ Wt,
    const float* __restrict__ bias, const float* __restrict__ bng,
    const float* __restrict__ bnb, unsigned short* __restrict__ resid,
    unsigned short* __restrict__ outb, int N, int K) {
  // per buffer: A[128*32] shorts @0, B[128*32] shorts @4096; 8192 shorts = 16KB
  __shared__ unsigned short smem[3 * 8192];
  const int tid = threadIdx.x;
  const int wave = tid >> 6, lane = tid & 63;

  // XCD-chunked swizzle (all grids have nwg % 8 == 0); bn is the fast dim so
  // one XCD owns all bn-blocks of a run of bm -> A-panel fetched once per XCD.
  const int bnN = gridDim.x;
  const int nwg = bnN * gridDim.y;
  int wg = blockIdx.y * bnN + blockIdx.x;
  const int chunk = nwg >> 3;
  wg = (wg & 7) * chunk + (wg >> 3);
  const int bn = wg % bnN;
  const int bm = wg / bnN;

  const int wm = wave >> 1, wn = wave & 1;
  const int laneRow = lane >> 2;      // 0..15
  const int scol = (lane & 3) * 8;    // shorts (16B per lane)
  const size_t aBase = (size_t)bm * 128;
  const size_t bBase = (size_t)bn * 128;

  f32x4 acc[4][4];
#pragma unroll
  for (int i = 0; i < 4; i++)
#pragma unroll
    for (int j = 0; j < 4; j++) acc[i][j] = f32x4{0.f, 0.f, 0.f, 0.f};

  // 4 global_load_lds per wave per step (2 for A's 32 rows, 2 for B's 32 rows)
  auto stage = [&](int buf, int kt) {
    const int k0 = kt << 5;
    unsigned short* sb = smem + buf * 8192;
#pragma unroll
    for (int r = 0; r < 2; ++r) {
      int row = wave * 32 + r * 16 + laneRow;
      __builtin_amdgcn_global_load_lds(
          (const __attribute__((address_space(1))) void*)(A + (aBase + row) * K + k0 + scol),
          (__attribute__((address_space(3))) void*)(sb + row * 32 + scol), 16, 0, 0);
    }
#pragma unroll
    for (int r = 0; r < 2; ++r) {
      int row = wave * 32 + r * 16 + laneRow;
      __builtin_amdgcn_global_load_lds(
          (const __attribute__((address_space(1))) void*)(Wt + (bBase + row) * K + k0 + scol),
          (__attribute__((address_space(3))) void*)(sb + 4096 + row * 32 + scol), 16, 0, 0);
    }
  };

  const int nK = K >> 5;
  stage(0, 0);
  if (nK > 1) {
    stage(1, 1);
    asm volatile("s_waitcnt vmcnt(4)" ::: "memory");
  } else {
    asm volatile("s_waitcnt vmcnt(0)" ::: "memory");
  }
  __builtin_amdgcn_s_barrier();
  asm volatile("" ::: "memory");

  const int fr = lane & 15, kh = (lane >> 4) * 8;
  for (int kt = 0; kt < nK; ++kt) {
    const int cur = kt % 3;
    const bool more2 = (kt + 2 < nK);
    if (more2) stage((kt + 2) % 3, kt + 2);  // depth-2 prefetch flies over compute

    const unsigned short* sb = smem + cur * 8192;
    bf16x8 af[4], bfr[4];
#pragma unroll
    for (int mi = 0; mi < 4; mi++)
      af[mi] = *(const bf16x8*)(sb + (wm * 64 + mi * 16 + fr) * 32 + kh);
#pragma unroll
    for (int ni = 0; ni < 4; ni++)
      bfr[ni] = *(const bf16x8*)(sb + 4096 + (wn * 64 + ni * 16 + fr) * 32 + kh);
#pragma unroll
    for (int mi = 0; mi < 4; mi++)
#pragma unroll
      for (int ni = 0; ni < 4; ni++)
        acc[mi][ni] = __builtin_amdgcn_mfma_f32_16x16x32_bf16(af[mi], bfr[ni], acc[mi][ni], 0, 0, 0);

    if (kt + 1 < nK) {
      if (more2) {
        asm volatile("s_waitcnt vmcnt(4)" ::: "memory");  // retire tile kt+1 only
      } else {
        asm volatile("s_waitcnt vmcnt(0)" ::: "memory");  // boundary drain (once)
      }
      __builtin_amdgcn_s_barrier();
      asm volatile("" ::: "memory");
    }
  }

  const int r4 = (lane >> 4) * 4;
  const float bnrs = 0.9999950000374997f;  // rsqrt(1 + 1e-5)

  // --- staged epilogue: LDS tile [128][128] shorts with row-XOR swizzle ---
  __syncthreads();  // all waves done reading K-loop smem
  unsigned short* esm = smem;  // 16384 shorts = 32KB <= 48KB
#pragma unroll
  for (int ni = 0; ni < 4; ni++) {
    int cl = wn * 64 + ni * 16 + fr;       // local col 0..127
    int cg = bn * 128 + cl;                // global col
    float bval = bias[cg];
    float sc = 0.f, sh = 0.f;
    if (EPI == 2 || EPI == 3) { sc = bng[cg] * bnrs; sh = bnb[cg]; }
#pragma unroll
    for (int mi = 0; mi < 4; mi++) {
#pragma unroll
      for (int j = 0; j < 4; j++) {
        int row = wm * 64 + mi * 16 + r4 + j;
        float v = acc[mi][ni][j] + bval;
        if (EPI == 2 || EPI == 3) v = gelu_f(v * sc + sh);
        esm[row * 128 + (cl ^ (((row >> 2) & 3) << 4))] = f2bf(v);
      }
    }
  }
  __syncthreads();
#pragma unroll
  for (int it = 0; it < 8; it++) {
    int idx = it * 256 + tid;
    int row = idx >> 4;
    int c0 = (idx & 15) * 8;
    int c0s = c0 ^ (((row >> 2) & 3) << 4);
    us8 v = *(const us8*)(esm + row * 128 + c0s);
    if (EPI == 0 || EPI == 2) {
      *(us8*)(outb + (aBase + row) * (size_t)N + bn * 128 + c0) = v;
    } else {
      // residual RMW on bf16 stream (N == 256), fully coalesced 16B/lane
      unsigned short* rp = resid + (aBase + row) * 256 + bn * 128 + c0;
      us8 tv = *(const us8*)rp;
      us8 o;
#pragma unroll
      for (int e = 0; e < 8; e++) o[e] = f2bf(bf2f(tv[e]) + bf2f(v[e]));
      *(us8*)rp = o;
    }
  }
}

// ---------------- windowed attention, register-resident (R13-proven) ----------------
// K,V f32 in LDS (25KB+25KB); rpe staged for ONLY this block's 4 heads (2.7KB)
// -> 51.7KB LDS -> 3 blocks/CU. VGPR 76, no spill (R13-verified, 78.7us).
// R9/R10/R14 lesson: ANY restructure adding concurrent live state spills. Do not touch.
__global__ __launch_bounds__(256, 2) void attn_kernel(const unsigned short* __restrict__ qkv,
                                                      const float* __restrict__ rpe,
                                                      unsigned short* __restrict__ y2) {
  __shared__ float ks[4 * 49 * 32];
  __shared__ float vs[4 * 49 * 32];
  __shared__ float rpet[4 * 169];  // [h_l][ridx]
  const int tid = threadIdx.x;
  const int blk = blockIdx.x;
  const int win = blk >> 1;
  const int hg = (blk & 1) * 4;
  const int b = win >> 8, rem = win & 255;
  const int ph = rem >> 4, pw = rem & 15;
  const size_t base = (size_t)b * HW_ + ph * 7 * 112 + pw * 7;

  for (int c = tid; c < 169 * 4; c += 256)
    rpet[(c & 3) * 169 + (c >> 2)] = rpe[(c >> 2) * 8 + hg + (c & 3)];
  for (int c = tid; c < 4 * 49 * 8; c += 256) {
    int h_l = c / (49 * 8);
    int r2 = c - h_l * (49 * 8);
    int tok = r2 >> 3, ch4 = r2 & 7;
    size_t m = base + (tok / 7) * 112 + (tok % 7);
    const unsigned short* kp = qkv + m * 768 + 256 + (hg + h_l) * 32 + ch4 * 4;
    us4 kv = *(const us4*)kp;
    us4 vv = *(const us4*)(kp + 256);
    float* kd = ks + (h_l * 49 + tok) * 32 + ch4 * 4;
    float* vd = vs + (h_l * 49 + tok) * 32 + ch4 * 4;
    kd[0] = bf2f(kv.x); kd[1] = bf2f(kv.y); kd[2] = bf2f(kv.z); kd[3] = bf2f(kv.w);
    vd[0] = bf2f(vv.x); vd[1] = bf2f(vv.y); vd[2] = bf2f(vv.z); vd[3] = bf2f(vv.w);
  }

  const int lane = tid & 63;
  const int h_l = tid >> 6;
  const int h = hg + h_l;
  const int qi = lane < 49 ? lane : 48;
  const size_t mq = base + (qi / 7) * 112 + (qi % 7);

  f32x4 q[8];
  {
    const unsigned short* qp = qkv + mq * 768 + h * 32;
    const float qsc = 0.17677669529663689f;  // 1/sqrt(32)
#pragma unroll
    for (int j = 0; j < 8; j++) {
      us4 v = *(const us4*)(qp + j * 4);
      q[j].x = bf2f(v.x) * qsc; q[j].y = bf2f(v.y) * qsc;
      q[j].z = bf2f(v.z) * qsc; q[j].w = bf2f(v.w) * qsc;
    }
  }
  __syncthreads();

  float S[49];
  const float* kbase = ks + h_l * 49 * 32;
#pragma unroll
  for (int ki = 0; ki < 49; ki++) {
    const f32x4* kr = (const f32x4*)(kbase + ki * 32);
    f32x4 a0 = {0.f, 0.f, 0.f, 0.f}, a1 = {0.f, 0.f, 0.f, 0.f};
#pragma unroll
    for (int j = 0; j < 4; j++) {
      a0 += q[2 * j] * kr[2 * j];
      a1 += q[2 * j + 1] * kr[2 * j + 1];
    }
    f32x4 as = a0 + a1;
    S[ki] = (as.x + as.z) + (as.y + as.w);
  }

  const int qr = qi / 7, qc = qi % 7;
  const float* rp = rpet + h_l * 169;
#pragma unroll
  for (int ki = 0; ki < 49; ki++) {
    int ridx = (qr - ki / 7 + 6) * 13 + (qc - ki % 7 + 6);
    S[ki] += rp[ridx];
  }
  float mx = S[0];
#pragma unroll
  for (int ki = 1; ki < 49; ki++) mx = fmaxf(mx, S[ki]);
  float sum = 0.f;
#pragma unroll
  for (int ki = 0; ki < 49; ki++) {
    float e = __expf(S[ki] - mx);
    S[ki] = e;
    sum += e;
  }
  float inv = 1.f / sum;

  f32x4 o[8];
#pragma unroll
  for (int j = 0; j < 8; j++) o[j] = f32x4{0.f, 0.f, 0.f, 0.f};
  const float* vbase = vs + h_l * 49 * 32;
#pragma unroll
  for (int k = 0; k < 49; k++) {
    const f32x4* vr = (const f32x4*)(vbase + k * 32);
    float p = S[k];
#pragma unroll
    for (int j = 0; j < 8; j++) o[j] += p * vr[j];
  }
#pragma unroll
  for (int j = 0; j < 8; j++) o[j] *= inv;

  if (lane < 49) {
    unsigned short* op = y2 + mq * 256 + h * 32;
#pragma unroll
    for (int j2 = 0; j2 < 4; j2++) {
      us8 pk;
      pk[0] = f2bf(o[2 * j2].x); pk[1] = f2bf(o[2 * j2].y);
      pk[2] = f2bf(o[2 * j2].z); pk[3] = f2bf(o[2 * j2].w);
      pk[4] = f2bf(o[2 * j2 + 1].x); pk[5] = f2bf(o[2 * j2 + 1].y);
      pk[6] = f2bf(o[2 * j2 + 1].z); pk[7] = f2bf(o[2 * j2 + 1].w);
      *((us8*)(op + j2 * 8)) = pk;
    }
  }
}

// ---------------- depthwise 3x3 + bias + BN + GELU, row-sweep ----------------
// R13: branch-free inner loop (clamped pointers + zeroed weights for invalid
// rows), pointer-bump addressing, unroll-3 to kill rotation movs.
__global__ __launch_bounds__(256) void dwconv_kernel(
    const unsigned short* __restrict__ h1, const float* __restrict__ wT,
    const float* __restrict__ bias, const float* __restrict__ bng,
    const float* __restrict__ bnb, unsigned short* __restrict__ h2) {
  const int blk = blockIdx.x;
  const int q = blk & 3;
  const int y = (blk >> 2) % 112;
  const int b = blk / (4 * 112);
  const int tid = threadIdx.x;
  const int c0 = tid * 4;
  const int x0 = q * 28;

  f32x4 wv[9];
#pragma unroll
  for (int wi = 0; wi < 9; wi++) wv[wi] = *(const f32x4*)(wT + wi * HID_ + c0);

  const float bnrs = 0.9999950000374997f;
  f32x4 bv = ((const f32x4*)bias)[tid];
  f32x4 sc = ((const f32x4*)bng)[tid];
  sc *= bnrs;
  f32x4 sh = ((const f32x4*)bnb)[tid];
  sh += bv * sc;

  const unsigned short* rp[3];
#pragma unroll
  for (int r = 0; r < 3; r++) {
    int yy = y - 1 + r;
    if ((unsigned)yy >= 112u) {
      yy = y;
      wv[r * 3 + 0] = f32x4{0.f, 0.f, 0.f, 0.f};
      wv[r * 3 + 1] = f32x4{0.f, 0.f, 0.f, 0.f};
      wv[r * 3 + 2] = f32x4{0.f, 0.f, 0.f, 0.f};
    }
    rp[r] = h1 + ((size_t)b * HW_ + (size_t)yy * 112 + x0) * HID_ + c0;
  }

  auto ld = [&](const unsigned short* p) -> f32x4 {
    us4 v = *(const us4*)p;
    f32x4 f;
    f.x = bf2f(v.x); f.y = bf2f(v.y); f.z = bf2f(v.z); f.w = bf2f(v.w);
    return f;
  };

  f32x4 colP[3], colC[3], colN[3];
  if (x0 > 0) {
#pragma unroll
    for (int r = 0; r < 3; r++) colP[r] = ld(rp[r] - HID_);
  } else {
#pragma unroll
    for (int r = 0; r < 3; r++) colP[r] = f32x4{0.f, 0.f, 0.f, 0.f};
  }
#pragma unroll
  for (int r = 0; r < 3; r++) colC[r] = ld(rp[r]);

  unsigned short* outp = h2 + ((size_t)b * HW_ + (size_t)y * 112 + x0) * HID_ + c0;

  auto convemit = [&](unsigned short* op) {
    f32x4 a = {0.f, 0.f, 0.f, 0.f};
#pragma unroll
    for (int r = 0; r < 3; r++) {
      a += colP[r] * wv[r * 3 + 0];
      a += colC[r] * wv[r * 3 + 1];
      a += colN[r] * wv[r * 3 + 2];
    }
    a = a * sc + sh;
    us4 o;
    o.x = f2bf(gelu_f(a.x));
    o.y = f2bf(gelu_f(a.y));
    o.z = f2bf(gelu_f(a.z));
    o.w = f2bf(gelu_f(a.w));
    *(us4*)op = o;
  };

#pragma unroll 3
  for (int i = 0; i < 27; ++i) {
#pragma unroll
    for (int r = 0; r < 3; r++) colN[r] = ld(rp[r] + (size_t)(i + 1) * HID_);
    convemit(outp + (size_t)i * HID_);
#pragma unroll
    for (int r = 0; r < 3; r++) { colP[r] = colC[r]; colC[r] = colN[r]; }
  }
  if (x0 + 28 < 112) {
#pragma unroll
    for (int r = 0; r < 3; r++) colN[r] = ld(rp[r] + (size_t)28 * HID_);
  } else {
#pragma unroll
    for (int r = 0; r < 3; r++) colN[r] = f32x4{0.f, 0.f, 0.f, 0.f};
  }
  convemit(outp + (size_t)27 * HID_);
}

extern "C" void kernel_launch(void* const* d_in, const int* in_sizes, int n_in,
                              void* d_out, int out_size, void* d_ws, size_t ws_size,
                              hipStream_t stream) {
  const float* x      = (const float*)d_in[0];
  const float* ln1_g  = (const float*)d_in[1];
  const float* ln1_b  = (const float*)d_in[2];
  const float* qkv_w  = (const float*)d_in[3];
  const float* qkv_b  = (const float*)d_in[4];
  const float* rpe    = (const float*)d_in[5];
  const float* proj_w = (const float*)d_in[6];
  const float* proj_b = (const float*)d_in[7];
  const float* ln2_g  = (const float*)d_in[8];
  const float* ln2_b  = (const float*)d_in[9];
  const float* c1_w   = (const float*)d_in[10];
  const float* c1_b   = (const float*)d_in[11];
  const float* bn1_g  = (const float*)d_in[12];
  const float* bn1_b  = (const float*)d_in[13];
  const float* dw_w   = (const float*)d_in[14];
  const float* dw_b   = (const float*)d_in[15];
  const float* bn2_g  = (const float*)d_in[16];
  const float* bn2_b  = (const float*)d_in[17];
  const float* c3_w   = (const float*)d_in[18];
  const float* c3_b   = (const float*)d_in[19];
  const float* bn3_g  = (const float*)d_in[20];
  const float* bn3_b  = (const float*)d_in[21];

  // ---- workspace layout (liveness-aliased; t now bf16) ----
  char* ws = (char*)d_ws;
  size_t off = 0;
  unsigned short* t = (unsigned short*)(ws + off);  off += (size_t)M_ * 256 * 2;
  unsigned short* S1 = (unsigned short*)(ws + off); off += (size_t)M_ * 1024 * 2;
  unsigned short* S2 = (unsigned short*)(ws + off); off += (size_t)M_ * 1024 * 2;
  unsigned short* yb = S2;  // alias: never live at the same time as S2
  unsigned short* wb_qkv  = (unsigned short*)(ws + off); off += (size_t)2 * 768 * 256 * 2;
  unsigned short* wb_proj = (unsigned short*)(ws + off); off += (size_t)2 * 256 * 256 * 2;
  unsigned short* wb_c1   = (unsigned short*)(ws + off); off += (size_t)2 * 1024 * 256 * 2;
  unsigned short* wb_c3   = (unsigned short*)(ws + off); off += (size_t)2 * 256 * 1024 * 2;
  float* wT = (float*)(ws + off);                   off += (size_t)2 * HID_ * 9 * 4;
  if (off > ws_size) return;  // clean failure instead of OOB crash

  // weight prep
  cast_bf16_kernel<<<384, 256, 0, stream>>>(qkv_w, wb_qkv, 2 * 768 * 256 / 4);
  cast_bf16_kernel<<<128, 256, 0, stream>>>(proj_w, wb_proj, 2 * 256 * 256 / 4);
  cast_bf16_kernel<<<512, 256, 0, stream>>>(c1_w, wb_c1, 2 * 1024 * 256 / 4);
  cast_bf16_kernel<<<512, 256, 0, stream>>>(c3_w, wb_c3, 2 * 256 * 1024 / 4);
  dwT_kernel<<<72, 256, 0, stream>>>(dw_w, wT);

  transpose_in_kernel<<<dim3(392, 8, 4), dim3(32, 8), 0, stream>>>(x, t);

  for (int i = 0; i < 2; i++) {
    ln_kernel<<<M_ / 4, 256, 0, stream>>>(t, ln1_g + i * 256, ln1_b + i * 256, yb);
    gemm_kernel<0><<<dim3(6, 392), 256, 0, stream>>>(
        yb, wb_qkv + (size_t)i * 768 * 256, qkv_b + i * 768, nullptr, nullptr,
        nullptr, S1, 768, 256);
    attn_kernel<<<2048, 256, 0, stream>>>(S1, rpe + (size_t)i * 169 * 8, yb);
    gemm_kernel<1><<<dim3(2, 392), 256, 0, stream>>>(
        yb, wb_proj + (size_t)i * 256 * 256, proj_b + i * 256, nullptr, nullptr,
        t, nullptr, 256, 256);
    ln_kernel<<<M_ / 4, 256, 0, stream>>>(t, ln2_g + i * 256, ln2_b + i * 256, yb);
    gemm_kernel<2><<<dim3(8, 392), 256, 0, stream>>>(
        yb, wb_c1 + (size_t)i * 1024 * 256, c1_b + i * 1024, bn1_g + i * 1024,
        bn1_b + i * 1024, nullptr, S1, 1024, 256);
    dwconv_kernel<<<4 * 112 * 4, 256, 0, stream>>>(S1, wT + (size_t)i * HID_ * 9,
                                                   dw_b + i * 1024, bn2_g + i * 1024,
                                                   bn2_b + i * 1024, S2);
    gemm_kernel<3><<<dim3(2, 392), 256, 0, stream>>>(
        S2, wb_c3 + (size_t)i * 256 * 1024, c3_b + i * 256, bn3_g + i * 256,
        bn3_b + i * 256, t, nullptr, 256, 1024);
  }

  transpose_out_kernel<<<dim3(392, 8, 4), dim3(32, 8), 0, stream>>>(t, (float*)d_out);
}

// Round 18
// 681.567 us; speedup vs baseline: 7.2611x; 1.0073x over previous
//
#include <hip/hip_runtime.h>

typedef __attribute__((ext_vector_type(4))) float f32x4;
typedef __attribute__((ext_vector_type(8))) __bf16 bf16x8;
typedef __attribute__((ext_vector_type(4))) unsigned short us4;
typedef __attribute__((ext_vector_type(8))) unsigned short us8;

#define DEVI static __device__ __forceinline__

constexpr int C_   = 256;
constexpr int HW_  = 112 * 112;   // 12544
constexpr int M_   = 4 * HW_;     // 50176 tokens
constexpr int HID_ = 1024;

DEVI unsigned short f2bf(float f) {
  unsigned u = __float_as_uint(f);
  u += 0x7fffu + ((u >> 16) & 1u);
  return (unsigned short)(u >> 16);
}
DEVI float bf2f(unsigned short s) { return __uint_as_float(((unsigned)s) << 16); }
// tanh-form GELU via v_exp_f32 (~9 VALU vs ~25 for erff); max dev ~3e-4
DEVI float gelu_f(float x) {
  float u = x * (0.7978845608028654f + 0.0356774081363001f * x * x);
  float e = __expf(2.f * u);
  float t = 1.f - 2.f / (e + 1.f);
  return 0.5f * x * (1.f + t);
}

// ---------------- fp32 -> bf16 cast (weights) ----------------
__global__ void cast_bf16_kernel(const float* __restrict__ src,
                                 unsigned short* __restrict__ dst, int n4) {
  int i = blockIdx.x * 256 + threadIdx.x;
  if (i < n4) {
    f32x4 v = ((const f32x4*)src)[i];
    us4 o;
    o.x = f2bf(v.x); o.y = f2bf(v.y); o.z = f2bf(v.z); o.w = f2bf(v.w);
    ((us4*)dst)[i] = o;
  }
}

// ---------------- dw weights (blk, c, 9) -> (blk, 9, c) ----------------
__global__ void dwT_kernel(const float* __restrict__ w, float* __restrict__ wT) {
  int i = blockIdx.x * 256 + threadIdx.x;
  if (i < 2 * HID_ * 9) {
    int blkI = i / (HID_ * 9), rem = i % (HID_ * 9);
    int c = rem / 9, wi = rem % 9;
    wT[blkI * HID_ * 9 + wi * HID_ + c] = w[i];
  }
}

// ---------------- (B,C,HW) fp32 -> (B,HW,C) bf16 residual ----------------
__global__ void transpose_in_kernel(const float* __restrict__ x,
                                    unsigned short* __restrict__ t) {
  __shared__ float tile[32][33];
  int b = blockIdx.z;
  int p0 = blockIdx.x * 32, c0 = blockIdx.y * 32;
  int tx = threadIdx.x, ty = threadIdx.y;
  const float* xb = x + (size_t)b * C_ * HW_;
#pragma unroll
  for (int i = 0; i < 4; i++)
    tile[ty + 8 * i][tx] = xb[(size_t)(c0 + ty + 8 * i) * HW_ + p0 + tx];
  __syncthreads();
  unsigned short* tb = t + (size_t)b * HW_ * C_;
#pragma unroll
  for (int i = 0; i < 4; i++)
    tb[(size_t)(p0 + ty + 8 * i) * C_ + c0 + tx] = f2bf(tile[tx][ty + 8 * i]);
}

// ---------------- (B,HW,C) bf16 -> (B,C,HW) fp32 output ----------------
__global__ void transpose_out_kernel(const unsigned short* __restrict__ t,
                                     float* __restrict__ out) {
  __shared__ float tile[32][33];
  int b = blockIdx.z;
  int p0 = blockIdx.x * 32, c0 = blockIdx.y * 32;
  int tx = threadIdx.x, ty = threadIdx.y;
  const unsigned short* tb = t + (size_t)b * HW_ * C_;
#pragma unroll
  for (int i = 0; i < 4; i++)
    tile[ty + 8 * i][tx] = bf2f(tb[(size_t)(p0 + ty + 8 * i) * C_ + c0 + tx]);
  __syncthreads();
  float* ob = out + (size_t)b * C_ * HW_;
#pragma unroll
  for (int i = 0; i < 4; i++)
    ob[(size_t)(c0 + ty + 8 * i) * HW_ + p0 + tx] = tile[tx][ty + 8 * i];
}

// ---------------- LayerNorm (bf16 in, bf16 out), one wave per row ----------------
__global__ void ln_kernel(const unsigned short* __restrict__ t, const float* __restrict__ g,
                          const float* __restrict__ bsh, unsigned short* __restrict__ out) {
  int row = blockIdx.x * 4 + (threadIdx.x >> 6);
  int lane = threadIdx.x & 63;
  const unsigned short* tr = t + (size_t)row * C_;
  us4 v4 = ((const us4*)tr)[lane];
  f32x4 v;
  v.x = bf2f(v4.x); v.y = bf2f(v4.y); v.z = bf2f(v4.z); v.w = bf2f(v4.w);
  float s  = v.x + v.y + v.z + v.w;
  float s2 = v.x * v.x + v.y * v.y + v.z * v.z + v.w * v.w;
#pragma unroll
  for (int off = 1; off < 64; off <<= 1) {
    s  += __shfl_xor(s, off);
    s2 += __shfl_xor(s2, off);
  }
  float mean = s * (1.f / 256.f);
  float var  = s2 * (1.f / 256.f) - mean * mean;
  float rstd = rsqrtf(var + 1e-6f);
  f32x4 gg = ((const f32x4*)g)[lane];
  f32x4 bb = ((const f32x4*)bsh)[lane];
  us4 o;
  o.x = f2bf((v.x - mean) * rstd * gg.x + bb.x);
  o.y = f2bf((v.y - mean) * rstd * gg.y + bb.y);
  o.z = f2bf((v.z - mean) * rstd * gg.z + bb.z);
  o.w = f2bf((v.w - mean) * rstd * gg.w + bb.w);
  ((us4*)(out + (size_t)row * C_))[lane] = o;
}

// ---------------- GEMM: out(M,N) = A(M,K) * Wt(N,K)^T, bf16 in, fp32 acc ----------------
// 128x128 block tile, 4 waves (2x2, 64x64 each), 3 LDS buffers (48KB -> 3 blocks/CU),
// depth-2 prefetch, counted vmcnt(4). XCD-chunked swizzle for A-panel L2 reuse.
// ALL epilogues staged through LDS -> 16B/lane coalesced I/O.
template <int EPI>
__global__ __launch_bounds__(256, 2) void gemm_kernel(
    const unsigned short* __restrict__ A, const unsigned short* __restrict__ Wt,
    const float* __restrict__ bias, const float* __restrict__ bng,
    const float* __restrict__ bnb, unsigned short* __restrict__ resid,
    unsigned short* __restrict__ outb, int N, int K) {
  // per buffer: A[128*32] shorts @0, B[128*32] shorts @4096; 8192 shorts = 16KB
  __shared__ unsigned short smem[3 * 8192];
  const int tid = threadIdx.x;
  const int wave = tid >> 6, lane = tid & 63;

  // XCD-chunked swizzle (all grids have nwg % 8 == 0)
  const int bnN = gridDim.x;
  const int nwg = bnN * gridDim.y;
  int wg = blockIdx.y * bnN + blockIdx.x;
  const int chunk = nwg >> 3;
  wg = (wg & 7) * chunk + (wg >> 3);
  const int bn = wg % bnN;
  const int bm = wg / bnN;

  const int wm = wave >> 1, wn = wave & 1;
  const int laneRow = lane >> 2;      // 0..15
  const int scol = (lane & 3) * 8;    // shorts (16B per lane)
  const size_t aBase = (size_t)bm * 128;
  const size_t bBase = (size_t)bn * 128;

  f32x4 acc[4][4];
#pragma unroll
  for (int i = 0; i < 4; i++)
#pragma unroll
    for (int j = 0; j < 4; j++) acc[i][j] = f32x4{0.f, 0.f, 0.f, 0.f};

  auto stage = [&](int buf, int kt) {
    const int k0 = kt << 5;
    unsigned short* sb = smem + buf * 8192;
#pragma unroll
    for (int r = 0; r < 2; ++r) {
      int row = wave * 32 + r * 16 + laneRow;
      __builtin_amdgcn_global_load_lds(
          (const __attribute__((address_space(1))) void*)(A + (aBase + row) * K + k0 + scol),
          (__attribute__((address_space(3))) void*)(sb + row * 32 + scol), 16, 0, 0);
    }
#pragma unroll
    for (int r = 0; r < 2; ++r) {
      int row = wave * 32 + r * 16 + laneRow;
      __builtin_amdgcn_global_load_lds(
          (const __attribute__((address_space(1))) void*)(Wt + (bBase + row) * K + k0 + scol),
          (__attribute__((address_space(3))) void*)(sb + 4096 + row * 32 + scol), 16, 0, 0);
    }
  };

  const int nK = K >> 5;
  stage(0, 0);
  if (nK > 1) {
    stage(1, 1);
    asm volatile("s_waitcnt vmcnt(4)" ::: "memory");
  } else {
    asm volatile("s_waitcnt vmcnt(0)" ::: "memory");
  }
  __builtin_amdgcn_s_barrier();
  asm volatile("" ::: "memory");

  const int fr = lane & 15, kh = (lane >> 4) * 8;
  for (int kt = 0; kt < nK; ++kt) {
    const int cur = kt % 3;
    const bool more2 = (kt + 2 < nK);
    if (more2) stage((kt + 2) % 3, kt + 2);  // depth-2 prefetch flies over compute

    const unsigned short* sb = smem + cur * 8192;
    bf16x8 af[4], bfr[4];
#pragma unroll
    for (int mi = 0; mi < 4; mi++)
      af[mi] = *(const bf16x8*)(sb + (wm * 64 + mi * 16 + fr) * 32 + kh);
#pragma unroll
    for (int ni = 0; ni < 4; ni++)
      bfr[ni] = *(const bf16x8*)(sb + 4096 + (wn * 64 + ni * 16 + fr) * 32 + kh);
#pragma unroll
    for (int mi = 0; mi < 4; mi++)
#pragma unroll
      for (int ni = 0; ni < 4; ni++)
        acc[mi][ni] = __builtin_amdgcn_mfma_f32_16x16x32_bf16(af[mi], bfr[ni], acc[mi][ni], 0, 0, 0);

    if (kt + 1 < nK) {
      if (more2) {
        asm volatile("s_waitcnt vmcnt(4)" ::: "memory");  // retire tile kt+1 only
      } else {
        asm volatile("s_waitcnt vmcnt(0)" ::: "memory");  // boundary drain (once)
      }
      __builtin_amdgcn_s_barrier();
      asm volatile("" ::: "memory");
    }
  }

  const int r4 = (lane >> 4) * 4;
  const float bnrs = 0.9999950000374997f;  // rsqrt(1 + 1e-5)

  // --- staged epilogue: LDS tile [128][128] shorts with row-XOR swizzle ---
  __syncthreads();  // all waves done reading K-loop smem
  unsigned short* esm = smem;  // 16384 shorts = 32KB <= 48KB
#pragma unroll
  for (int ni = 0; ni < 4; ni++) {
    int cl = wn * 64 + ni * 16 + fr;       // local col 0..127
    int cg = bn * 128 + cl;                // global col
    float bval = bias[cg];
    float sc = 0.f, sh = 0.f;
    if (EPI == 2 || EPI == 3) { sc = bng[cg] * bnrs; sh = bnb[cg]; }
#pragma unroll
    for (int mi = 0; mi < 4; mi++) {
#pragma unroll
      for (int j = 0; j < 4; j++) {
        int row = wm * 64 + mi * 16 + r4 + j;
        float v = acc[mi][ni][j] + bval;
        if (EPI == 2 || EPI == 3) v = gelu_f(v * sc + sh);
        esm[row * 128 + (cl ^ (((row >> 2) & 3) << 4))] = f2bf(v);
      }
    }
  }
  __syncthreads();
#pragma unroll
  for (int it = 0; it < 8; it++) {
    int idx = it * 256 + tid;
    int row = idx >> 4;
    int c0 = (idx & 15) * 8;
    int c0s = c0 ^ (((row >> 2) & 3) << 4);
    us8 v = *(const us8*)(esm + row * 128 + c0s);
    if (EPI == 0 || EPI == 2) {
      *(us8*)(outb + (aBase + row) * (size_t)N + bn * 128 + c0) = v;
    } else {
      // residual RMW on bf16 stream (N == 256), fully coalesced 16B/lane
      unsigned short* rp = resid + (aBase + row) * 256 + bn * 128 + c0;
      us8 tv = *(const us8*)rp;
      us8 o;
#pragma unroll
      for (int e = 0; e < 8; e++) o[e] = f2bf(bf2f(tv[e]) + bf2f(v[e]));
      *(us8*)rp = o;
    }
  }
}

// ---------------- windowed attention, register-resident (R13-proven) ----------------
// K,V f32 in LDS (25KB+25KB); rpe staged for ONLY this block's 4 heads (2.7KB)
// -> 51.7KB LDS -> 3 blocks/CU. VGPR 76, no spill (R13-verified, 78.7us).
// R9/R10/R14 lesson: ANY restructure adding concurrent live state spills. Do not touch.
__global__ __launch_bounds__(256, 2) void attn_kernel(const unsigned short* __restrict__ qkv,
                                                      const float* __restrict__ rpe,
                                                      unsigned short* __restrict__ y2) {
  __shared__ float ks[4 * 49 * 32];
  __shared__ float vs[4 * 49 * 32];
  __shared__ float rpet[4 * 169];  // [h_l][ridx]
  const int tid = threadIdx.x;
  const int blk = blockIdx.x;
  const int win = blk >> 1;
  const int hg = (blk & 1) * 4;
  const int b = win >> 8, rem = win & 255;
  const int ph = rem >> 4, pw = rem & 15;
  const size_t base = (size_t)b * HW_ + ph * 7 * 112 + pw * 7;

  for (int c = tid; c < 169 * 4; c += 256)
    rpet[(c & 3) * 169 + (c >> 2)] = rpe[(c >> 2) * 8 + hg + (c & 3)];
  for (int c = tid; c < 4 * 49 * 8; c += 256) {
    int h_l = c / (49 * 8);
    int r2 = c - h_l * (49 * 8);
    int tok = r2 >> 3, ch4 = r2 & 7;
    size_t m = base + (tok / 7) * 112 + (tok % 7);
    const unsigned short* kp = qkv + m * 768 + 256 + (hg + h_l) * 32 + ch4 * 4;
    us4 kv = *(const us4*)kp;
    us4 vv = *(const us4*)(kp + 256);
    float* kd = ks + (h_l * 49 + tok) * 32 + ch4 * 4;
    float* vd = vs + (h_l * 49 + tok) * 32 + ch4 * 4;
    kd[0] = bf2f(kv.x); kd[1] = bf2f(kv.y); kd[2] = bf2f(kv.z); kd[3] = bf2f(kv.w);
    vd[0] = bf2f(vv.x); vd[1] = bf2f(vv.y); vd[2] = bf2f(vv.z); vd[3] = bf2f(vv.w);
  }

  const int lane = tid & 63;
  const int h_l = tid >> 6;
  const int h = hg + h_l;
  const int qi = lane < 49 ? lane : 48;
  const size_t mq = base + (qi / 7) * 112 + (qi % 7);

  f32x4 q[8];
  {
    const unsigned short* qp = qkv + mq * 768 + h * 32;
    const float qsc = 0.17677669529663689f;  // 1/sqrt(32)
#pragma unroll
    for (int j = 0; j < 8; j++) {
      us4 v = *(const us4*)(qp + j * 4);
      q[j].x = bf2f(v.x) * qsc; q[j].y = bf2f(v.y) * qsc;
      q[j].z = bf2f(v.z) * qsc; q[j].w = bf2f(v.w) * qsc;
    }
  }
  __syncthreads();

  float S[49];
  const float* kbase = ks + h_l * 49 * 32;
#pragma unroll
  for (int ki = 0; ki < 49; ki++) {
    const f32x4* kr = (const f32x4*)(kbase + ki * 32);
    f32x4 a0 = {0.f, 0.f, 0.f, 0.f}, a1 = {0.f, 0.f, 0.f, 0.f};
#pragma unroll
    for (int j = 0; j < 4; j++) {
      a0 += q[2 * j] * kr[2 * j];
      a1 += q[2 * j + 1] * kr[2 * j + 1];
    }
    f32x4 as = a0 + a1;
    S[ki] = (as.x + as.z) + (as.y + as.w);
  }

  const int qr = qi / 7, qc = qi % 7;
  const float* rp = rpet + h_l * 169;
#pragma unroll
  for (int ki = 0; ki < 49; ki++) {
    int ridx = (qr - ki / 7 + 6) * 13 + (qc - ki % 7 + 6);
    S[ki] += rp[ridx];
  }
  float mx = S[0];
#pragma unroll
  for (int ki = 1; ki < 49; ki++) mx = fmaxf(mx, S[ki]);
  float sum = 0.f;
#pragma unroll
  for (int ki = 0; ki < 49; ki++) {
    float e = __expf(S[ki] - mx);
    S[ki] = e;
    sum += e;
  }
  float inv = 1.f / sum;

  f32x4 o[8];
#pragma unroll
  for (int j = 0; j < 8; j++) o[j] = f32x4{0.f, 0.f, 0.f, 0.f};
  const float* vbase = vs + h_l * 49 * 32;
#pragma unroll
  for (int k = 0; k < 49; k++) {
    const f32x4* vr = (const f32x4*)(vbase + k * 32);
    float p = S[k];
#pragma unroll
    for (int j = 0; j < 8; j++) o[j] += p * vr[j];
  }
#pragma unroll
  for (int j = 0; j < 8; j++) o[j] *= inv;

  if (lane < 49) {
    unsigned short* op = y2 + mq * 256 + h * 32;
#pragma unroll
    for (int j2 = 0; j2 < 4; j2++) {
      us8 pk;
      pk[0] = f2bf(o[2 * j2].x); pk[1] = f2bf(o[2 * j2].y);
      pk[2] = f2bf(o[2 * j2].z); pk[3] = f2bf(o[2 * j2].w);
      pk[4] = f2bf(o[2 * j2 + 1].x); pk[5] = f2bf(o[2 * j2 + 1].y);
      pk[6] = f2bf(o[2 * j2 + 1].z); pk[7] = f2bf(o[2 * j2 + 1].w);
      *((us8*)(op + j2 * 8)) = pk;
    }
  }
}

// ---------------- depthwise 3x3 + bias + BN + GELU, pixel-pair row-sweep ----------------
// R17: process pixel PAIRS (shared column window A,B,C,D) -> halves rotation movs
// and loop/address overhead vs per-pixel sweep. Invalid rows still handled by
// clamped pointers + zeroed weights (branch-free loads). VGPR ~60, no spill risk.
__global__ __launch_bounds__(256) void dwconv_kernel(
    const unsigned short* __restrict__ h1, const float* __restrict__ wT,
    const float* __restrict__ bias, const float* __restrict__ bng,
    const float* __restrict__ bnb, unsigned short* __restrict__ h2) {
  const int blk = blockIdx.x;
  const int q = blk & 3;
  const int y = (blk >> 2) % 112;
  const int b = blk / (4 * 112);
  const int tid = threadIdx.x;
  const int c0 = tid * 4;
  const int x0 = q * 28;

  f32x4 wv[9];
#pragma unroll
  for (int wi = 0; wi < 9; wi++) wv[wi] = *(const f32x4*)(wT + wi * HID_ + c0);

  const float bnrs = 0.9999950000374997f;
  f32x4 bv = ((const f32x4*)bias)[tid];
  f32x4 sc = ((const f32x4*)bng)[tid];
  sc *= bnrs;
  f32x4 sh = ((const f32x4*)bnb)[tid];
  sh += bv * sc;

  const unsigned short* rp[3];
#pragma unroll
  for (int r = 0; r < 3; r++) {
    int yy = y - 1 + r;
    if ((unsigned)yy >= 112u) {
      yy = y;
      wv[r * 3 + 0] = f32x4{0.f, 0.f, 0.f, 0.f};
      wv[r * 3 + 1] = f32x4{0.f, 0.f, 0.f, 0.f};
      wv[r * 3 + 2] = f32x4{0.f, 0.f, 0.f, 0.f};
    }
    rp[r] = h1 + ((size_t)b * HW_ + (size_t)yy * 112 + x0) * HID_ + c0;
  }

  auto ld = [&](const unsigned short* p) -> f32x4 {
    us4 v = *(const us4*)p;
    f32x4 f;
    f.x = bf2f(v.x); f.y = bf2f(v.y); f.z = bf2f(v.z); f.w = bf2f(v.w);
    return f;
  };

  f32x4 cA[3], cB[3], cC[3], cD[3];
  if (x0 > 0) {
#pragma unroll
    for (int r = 0; r < 3; r++) cA[r] = ld(rp[r] - HID_);
  } else {
#pragma unroll
    for (int r = 0; r < 3; r++) cA[r] = f32x4{0.f, 0.f, 0.f, 0.f};
  }
#pragma unroll
  for (int r = 0; r < 3; r++) cB[r] = ld(rp[r]);

  unsigned short* outp = h2 + ((size_t)b * HW_ + (size_t)y * 112 + x0) * HID_ + c0;

  auto emit = [&](const f32x4* l, const f32x4* m, const f32x4* rr,
                  unsigned short* op) {
    f32x4 a = {0.f, 0.f, 0.f, 0.f};
#pragma unroll
    for (int r = 0; r < 3; r++) {
      a += l[r] * wv[r * 3 + 0];
      a += m[r] * wv[r * 3 + 1];
      a += rr[r] * wv[r * 3 + 2];
    }
    a = a * sc + sh;
    us4 o;
    o.x = f2bf(gelu_f(a.x));
    o.y = f2bf(gelu_f(a.y));
    o.z = f2bf(gelu_f(a.z));
    o.w = f2bf(gelu_f(a.w));
    *(us4*)op = o;
  };

  // 14 pixel-pairs; pairs 0..12 have unconditionally valid loads (x+2 <= 110)
#pragma unroll 2
  for (int k = 0; k < 13; ++k) {
#pragma unroll
    for (int r = 0; r < 3; r++) {
      cC[r] = ld(rp[r] + (size_t)(2 * k + 1) * HID_);
      cD[r] = ld(rp[r] + (size_t)(2 * k + 2) * HID_);
    }
    emit(cA, cB, cC, outp + (size_t)(2 * k) * HID_);
    emit(cB, cC, cD, outp + (size_t)(2 * k + 1) * HID_);
#pragma unroll
    for (int r = 0; r < 3; r++) { cA[r] = cC[r]; cB[r] = cD[r]; }
  }
  // last pair (x = x0+26, x0+27): right neighbor of x0+27 exists unless q == 3
#pragma unroll
  for (int r = 0; r < 3; r++) cC[r] = ld(rp[r] + (size_t)27 * HID_);
  if (x0 + 28 < 112) {
#pragma unroll
    for (int r = 0; r < 3; r++) cD[r] = ld(rp[r] + (size_t)28 * HID_);
  } else {
#pragma unroll
    for (int r = 0; r < 3; r++) cD[r] = f32x4{0.f, 0.f, 0.f, 0.f};
  }
  emit(cA, cB, cC, outp + (size_t)26 * HID_);
  emit(cB, cC, cD, outp + (size_t)27 * HID_);
}

extern "C" void kernel_launch(void* const* d_in, const int* in_sizes, int n_in,
                              void* d_out, int out_size, void* d_ws, size_t ws_size,
                              hipStream_t stream) {
  const float* x      = (const float*)d_in[0];
  const float* ln1_g  = (const float*)d_in[1];
  const float* ln1_b  = (const float*)d_in[2];
  const float* qkv_w  = (const float*)d_in[3];
  const float* qkv_b  = (const float*)d_in[4];
  const float* rpe    = (const float*)d_in[5];
  const float* proj_w = (const float*)d_in[6];
  const float* proj_b = (const float*)d_in[7];
  const float* ln2_g  = (const float*)d_in[8];
  const float* ln2_b  = (const float*)d_in[9];
  const float* c1_w   = (const float*)d_in[10];
  const float* c1_b   = (const float*)d_in[11];
  const float* bn1_g  = (const float*)d_in[12];
  const float* bn1_b  = (const float*)d_in[13];
  const float* dw_w   = (const float*)d_in[14];
  const float* dw_b   = (const float*)d_in[15];
  const float* bn2_g  = (const float*)d_in[16];
  const float* bn2_b  = (const float*)d_in[17];
  const float* c3_w   = (const float*)d_in[18];
  const float* c3_b   = (const float*)d_in[19];
  const float* bn3_g  = (const float*)d_in[20];
  const float* bn3_b  = (const float*)d_in[21];

  // ---- workspace layout (liveness-aliased; t bf16) ----
  char* ws = (char*)d_ws;
  size_t off = 0;
  unsigned short* t = (unsigned short*)(ws + off);  off += (size_t)M_ * 256 * 2;
  unsigned short* S1 = (unsigned short*)(ws + off); off += (size_t)M_ * 1024 * 2;
  unsigned short* S2 = (unsigned short*)(ws + off); off += (size_t)M_ * 1024 * 2;
  unsigned short* yb = S2;  // alias: never live at the same time as S2
  unsigned short* wb_qkv  = (unsigned short*)(ws + off); off += (size_t)2 * 768 * 256 * 2;
  unsigned short* wb_proj = (unsigned short*)(ws + off); off += (size_t)2 * 256 * 256 * 2;
  unsigned short* wb_c1   = (unsigned short*)(ws + off); off += (size_t)2 * 1024 * 256 * 2;
  unsigned short* wb_c3   = (unsigned short*)(ws + off); off += (size_t)2 * 256 * 1024 * 2;
  float* wT = (float*)(ws + off);                   off += (size_t)2 * HID_ * 9 * 4;
  if (off > ws_size) return;  // clean failure instead of OOB crash

  // weight prep
  cast_bf16_kernel<<<384, 256, 0, stream>>>(qkv_w, wb_qkv, 2 * 768 * 256 / 4);
  cast_bf16_kernel<<<128, 256, 0, stream>>>(proj_w, wb_proj, 2 * 256 * 256 / 4);
  cast_bf16_kernel<<<512, 256, 0, stream>>>(c1_w, wb_c1, 2 * 1024 * 256 / 4);
  cast_bf16_kernel<<<512, 256, 0, stream>>>(c3_w, wb_c3, 2 * 256 * 1024 / 4);
  dwT_kernel<<<72, 256, 0, stream>>>(dw_w, wT);

  transpose_in_kernel<<<dim3(392, 8, 4), dim3(32, 8), 0, stream>>>(x, t);

  for (int i = 0; i < 2; i++) {
    ln_kernel<<<M_ / 4, 256, 0, stream>>>(t, ln1_g + i * 256, ln1_b + i * 256, yb);
    gemm_kernel<0><<<dim3(6, 392), 256, 0, stream>>>(
        yb, wb_qkv + (size_t)i * 768 * 256, qkv_b + i * 768, nullptr, nullptr,
        nullptr, S1, 768, 256);
    attn_kernel<<<2048, 256, 0, stream>>>(S1, rpe + (size_t)i * 169 * 8, yb);
    gemm_kernel<1><<<dim3(2, 392), 256, 0, stream>>>(
        yb, wb_proj + (size_t)i * 256 * 256, proj_b + i * 256, nullptr, nullptr,
        t, nullptr, 256, 256);
    ln_kernel<<<M_ / 4, 256, 0, stream>>>(t, ln2_g + i * 256, ln2_b + i * 256, yb);
    gemm_kernel<2><<<dim3(8, 392), 256, 0, stream>>>(
        yb, wb_c1 + (size_t)i * 1024 * 256, c1_b + i * 1024, bn1_g + i * 1024,
        bn1_b + i * 1024, nullptr, S1, 1024, 256);
    dwconv_kernel<<<4 * 112 * 4, 256, 0, stream>>>(S1, wT + (size_t)i * HID_ * 9,
                                                   dw_b + i * 1024, bn2_g + i * 1024,
                                                   bn2_b + i * 1024, S2);
    gemm_kernel<3><<<dim3(2, 392), 256, 0, stream>>>(
        S2, wb_c3 + (size_t)i * 256 * 1024, c3_b + i * 256, bn3_g + i * 256,
        bn3_b + i * 256, t, nullptr, 256, 1024);
  }

  transpose_out_kernel<<<dim3(392, 8, 4), dim3(32, 8), 0, stream>>>(t, (float*)d_out);
}

// Round 19
// 670.890 us; speedup vs baseline: 7.3767x; 1.0159x over previous
//
#include <hip/hip_runtime.h>

typedef __attribute__((ext_vector_type(4))) float f32x4;
typedef __attribute__((ext_vector_type(8))) __bf16 bf16x8;
typedef __attribute__((ext_vector_type(4))) unsigned short us4;
typedef __attribute__((ext_vector_type(8))) unsigned short us8;

#define DEVI static __device__ __forceinline__

constexpr int C_   = 256;
constexpr int HW_  = 112 * 112;   // 12544
constexpr int M_   = 4 * HW_;     // 50176 tokens
constexpr int HID_ = 1024;

// native bf16 convert (RNE) -> compiler emits v_cvt_pk_bf16_f32 where possible
DEVI unsigned short f2bf(float f) {
  __bf16 h = (__bf16)f;
  return __builtin_bit_cast(unsigned short, h);
}
DEVI float bf2f(unsigned short s) { return __uint_as_float(((unsigned)s) << 16); }
// tanh-form GELU via v_exp_f32 (~9 VALU vs ~25 for erff); max dev ~3e-4
DEVI float gelu_f(float x) {
  float u = x * (0.7978845608028654f + 0.0356774081363001f * x * x);
  float e = __expf(2.f * u);
  float t = 1.f - 2.f / (e + 1.f);
  return 0.5f * x * (1.f + t);
}

// ---------------- fp32 -> bf16 cast (weights) ----------------
__global__ void cast_bf16_kernel(const float* __restrict__ src,
                                 unsigned short* __restrict__ dst, int n4) {
  int i = blockIdx.x * 256 + threadIdx.x;
  if (i < n4) {
    f32x4 v = ((const f32x4*)src)[i];
    us4 o;
    o.x = f2bf(v.x); o.y = f2bf(v.y); o.z = f2bf(v.z); o.w = f2bf(v.w);
    ((us4*)dst)[i] = o;
  }
}

// ---------------- dw weights (blk, c, 9) -> (blk, 9, c) ----------------
__global__ void dwT_kernel(const float* __restrict__ w, float* __restrict__ wT) {
  int i = blockIdx.x * 256 + threadIdx.x;
  if (i < 2 * HID_ * 9) {
    int blkI = i / (HID_ * 9), rem = i % (HID_ * 9);
    int c = rem / 9, wi = rem % 9;
    wT[blkI * HID_ * 9 + wi * HID_ + c] = w[i];
  }
}

// ---------------- (B,C,HW) fp32 -> (B,HW,C) bf16 residual ----------------
__global__ void transpose_in_kernel(const float* __restrict__ x,
                                    unsigned short* __restrict__ t) {
  __shared__ float tile[32][33];
  int b = blockIdx.z;
  int p0 = blockIdx.x * 32, c0 = blockIdx.y * 32;
  int tx = threadIdx.x, ty = threadIdx.y;
  const float* xb = x + (size_t)b * C_ * HW_;
#pragma unroll
  for (int i = 0; i < 4; i++)
    tile[ty + 8 * i][tx] = xb[(size_t)(c0 + ty + 8 * i) * HW_ + p0 + tx];
  __syncthreads();
  unsigned short* tb = t + (size_t)b * HW_ * C_;
#pragma unroll
  for (int i = 0; i < 4; i++)
    tb[(size_t)(p0 + ty + 8 * i) * C_ + c0 + tx] = f2bf(tile[tx][ty + 8 * i]);
}

// ---------------- (B,HW,C) bf16 -> (B,C,HW) fp32 output ----------------
__global__ void transpose_out_kernel(const unsigned short* __restrict__ t,
                                     float* __restrict__ out) {
  __shared__ float tile[32][33];
  int b = blockIdx.z;
  int p0 = blockIdx.x * 32, c0 = blockIdx.y * 32;
  int tx = threadIdx.x, ty = threadIdx.y;
  const unsigned short* tb = t + (size_t)b * HW_ * C_;
#pragma unroll
  for (int i = 0; i < 4; i++)
    tile[ty + 8 * i][tx] = bf2f(tb[(size_t)(p0 + ty + 8 * i) * C_ + c0 + tx]);
  __syncthreads();
  float* ob = out + (size_t)b * C_ * HW_;
#pragma unroll
  for (int i = 0; i < 4; i++)
    ob[(size_t)(c0 + ty + 8 * i) * HW_ + p0 + tx] = tile[tx][ty + 8 * i];
}

// ---------------- LayerNorm (bf16 in, bf16 out), one wave per row ----------------
__global__ void ln_kernel(const unsigned short* __restrict__ t, const float* __restrict__ g,
                          const float* __restrict__ bsh, unsigned short* __restrict__ out) {
  int row = blockIdx.x * 4 + (threadIdx.x >> 6);
  int lane = threadIdx.x & 63;
  const unsigned short* tr = t + (size_t)row * C_;
  us4 v4 = ((const us4*)tr)[lane];
  f32x4 v;
  v.x = bf2f(v4.x); v.y = bf2f(v4.y); v.z = bf2f(v4.z); v.w = bf2f(v4.w);
  float s  = v.x + v.y + v.z + v.w;
  float s2 = v.x * v.x + v.y * v.y + v.z * v.z + v.w * v.w;
#pragma unroll
  for (int off = 1; off < 64; off <<= 1) {
    s  += __shfl_xor(s, off);
    s2 += __shfl_xor(s2, off);
  }
  float mean = s * (1.f / 256.f);
  float var  = s2 * (1.f / 256.f) - mean * mean;
  float rstd = rsqrtf(var + 1e-6f);
  f32x4 gg = ((const f32x4*)g)[lane];
  f32x4 bb = ((const f32x4*)bsh)[lane];
  us4 o;
  o.x = f2bf((v.x - mean) * rstd * gg.x + bb.x);
  o.y = f2bf((v.y - mean) * rstd * gg.y + bb.y);
  o.z = f2bf((v.z - mean) * rstd * gg.z + bb.z);
  o.w = f2bf((v.w - mean) * rstd * gg.w + bb.w);
  ((us4*)(out + (size_t)row * C_))[lane] = o;
}

// ---------------- GEMM: out(M,N) = A(M,K) * Wt(N,K)^T, bf16 in, fp32 acc ----------------
// 128x128 block tile, 4 waves (2x2, 64x64 each), 3 LDS buffers (48KB -> 3 blocks/CU),
// depth-2 prefetch, counted vmcnt(4). XCD-chunked swizzle for A-panel L2 reuse.
// ALL epilogues staged through LDS -> 16B/lane coalesced I/O.
template <int EPI>
__global__ __launch_bounds__(256, 2) void gemm_kernel(
    const unsigned short* __restrict__ A, const unsigned short* __restrict__ Wt,
    const float* __restrict__ bias, const float* __restrict__ bng,
    const float* __restrict__ bnb, unsigned short* __restrict__ resid,
    unsigned short* __restrict__ outb, int N, int K) {
  // per buffer: A[128*32] shorts @0, B[128*32] shorts @4096; 8192 shorts = 16KB
  __shared__ unsigned short smem[3 * 8192];
  const int tid = threadIdx.x;
  const int wave = tid >> 6, lane = tid & 63;

  // XCD-chunked swizzle (all grids have nwg % 8 == 0)
  const int bnN = gridDim.x;
  const int nwg = bnN * gridDim.y;
  int wg = blockIdx.y * bnN + blockIdx.x;
  const int chunk = nwg >> 3;
  wg = (wg & 7) * chunk + (wg >> 3);
  const int bn = wg % bnN;
  const int bm = wg / bnN;

  const int wm = wave >> 1, wn = wave & 1;
  const int laneRow = lane >> 2;      // 0..15
  const int scol = (lane & 3) * 8;    // shorts (16B per lane)
  const size_t aBase = (size_t)bm * 128;
  const size_t bBase = (size_t)bn * 128;

  f32x4 acc[4][4];
#pragma unroll
  for (int i = 0; i < 4; i++)
#pragma unroll
    for (int j = 0; j < 4; j++) acc[i][j] = f32x4{0.f, 0.f, 0.f, 0.f};

  auto stage = [&](int buf, int kt) {
    const int k0 = kt << 5;
    unsigned short* sb = smem + buf * 8192;
#pragma unroll
    for (int r = 0; r < 2; ++r) {
      int row = wave * 32 + r * 16 + laneRow;
      __builtin_amdgcn_global_load_lds(
          (const __attribute__((address_space(1))) void*)(A + (aBase + row) * K + k0 + scol),
          (__attribute__((address_space(3))) void*)(sb + row * 32 + scol), 16, 0, 0);
    }
#pragma unroll
    for (int r = 0; r < 2; ++r) {
      int row = wave * 32 + r * 16 + laneRow;
      __builtin_amdgcn_global_load_lds(
          (const __attribute__((address_space(1))) void*)(Wt + (bBase + row) * K + k0 + scol),
          (__attribute__((address_space(3))) void*)(sb + 4096 + row * 32 + scol), 16, 0, 0);
    }
  };

  const int nK = K >> 5;
  stage(0, 0);
  if (nK > 1) {
    stage(1, 1);
    asm volatile("s_waitcnt vmcnt(4)" ::: "memory");
  } else {
    asm volatile("s_waitcnt vmcnt(0)" ::: "memory");
  }
  __builtin_amdgcn_s_barrier();
  asm volatile("" ::: "memory");

  const int fr = lane & 15, kh = (lane >> 4) * 8;
  for (int kt = 0; kt < nK; ++kt) {
    const int cur = kt % 3;
    const bool more2 = (kt + 2 < nK);
    if (more2) stage((kt + 2) % 3, kt + 2);  // depth-2 prefetch flies over compute

    const unsigned short* sb = smem + cur * 8192;
    bf16x8 af[4], bfr[4];
#pragma unroll
    for (int mi = 0; mi < 4; mi++)
      af[mi] = *(const bf16x8*)(sb + (wm * 64 + mi * 16 + fr) * 32 + kh);
#pragma unroll
    for (int ni = 0; ni < 4; ni++)
      bfr[ni] = *(const bf16x8*)(sb + 4096 + (wn * 64 + ni * 16 + fr) * 32 + kh);
#pragma unroll
    for (int mi = 0; mi < 4; mi++)
#pragma unroll
      for (int ni = 0; ni < 4; ni++)
        acc[mi][ni] = __builtin_amdgcn_mfma_f32_16x16x32_bf16(af[mi], bfr[ni], acc[mi][ni], 0, 0, 0);

    if (kt + 1 < nK) {
      if (more2) {
        asm volatile("s_waitcnt vmcnt(4)" ::: "memory");  // retire tile kt+1 only
      } else {
        asm volatile("s_waitcnt vmcnt(0)" ::: "memory");  // boundary drain (once)
      }
      __builtin_amdgcn_s_barrier();
      asm volatile("" ::: "memory");
    }
  }

  const int r4 = (lane >> 4) * 4;
  const float bnrs = 0.9999950000374997f;  // rsqrt(1 + 1e-5)

  // --- staged epilogue: LDS tile [128][128] shorts with row-XOR swizzle ---
  __syncthreads();  // all waves done reading K-loop smem
  unsigned short* esm = smem;  // 16384 shorts = 32KB <= 48KB
#pragma unroll
  for (int ni = 0; ni < 4; ni++) {
    int cl = wn * 64 + ni * 16 + fr;       // local col 0..127
    int cg = bn * 128 + cl;                // global col
    float bval = bias[cg];
    float sc = 0.f, sh = 0.f;
    if (EPI == 2 || EPI == 3) { sc = bng[cg] * bnrs; sh = bnb[cg]; }
#pragma unroll
    for (int mi = 0; mi < 4; mi++) {
#pragma unroll
      for (int j = 0; j < 4; j++) {
        int row = wm * 64 + mi * 16 + r4 + j;
        float v = acc[mi][ni][j] + bval;
        if (EPI == 2 || EPI == 3) v = gelu_f(v * sc + sh);
        esm[row * 128 + (cl ^ (((row >> 2) & 3) << 4))] = f2bf(v);
      }
    }
  }
  __syncthreads();
#pragma unroll
  for (int it = 0; it < 8; it++) {
    int idx = it * 256 + tid;
    int row = idx >> 4;
    int c0 = (idx & 15) * 8;
    int c0s = c0 ^ (((row >> 2) & 3) << 4);
    us8 v = *(const us8*)(esm + row * 128 + c0s);
    if (EPI == 0 || EPI == 2) {
      *(us8*)(outb + (aBase + row) * (size_t)N + bn * 128 + c0) = v;
    } else {
      // residual RMW on bf16 stream (N == 256), fully coalesced 16B/lane
      unsigned short* rp = resid + (aBase + row) * 256 + bn * 128 + c0;
      us8 tv = *(const us8*)rp;
      us8 o;
#pragma unroll
      for (int e = 0; e < 8; e++) o[e] = f2bf(bf2f(tv[e]) + bf2f(v[e]));
      *(us8*)rp = o;
    }
  }
}

// ---------------- windowed attention, register-resident (R13-proven) ----------------
// K,V f32 in LDS (25KB+25KB); rpe staged for ONLY this block's 4 heads (2.7KB)
// -> 51.7KB LDS -> 3 blocks/CU. VGPR 76, no spill (R13-verified, 78.7us).
// R9/R10/R14 lesson: ANY restructure adding concurrent live state spills. Do not touch.
__global__ __launch_bounds__(256, 2) void attn_kernel(const unsigned short* __restrict__ qkv,
                                                      const float* __restrict__ rpe,
                                                      unsigned short* __restrict__ y2) {
  __shared__ float ks[4 * 49 * 32];
  __shared__ float vs[4 * 49 * 32];
  __shared__ float rpet[4 * 169];  // [h_l][ridx]
  const int tid = threadIdx.x;
  const int blk = blockIdx.x;
  const int win = blk >> 1;
  const int hg = (blk & 1) * 4;
  const int b = win >> 8, rem = win & 255;
  const int ph = rem >> 4, pw = rem & 15;
  const size_t base = (size_t)b * HW_ + ph * 7 * 112 + pw * 7;

  for (int c = tid; c < 169 * 4; c += 256)
    rpet[(c & 3) * 169 + (c >> 2)] = rpe[(c >> 2) * 8 + hg + (c & 3)];
  for (int c = tid; c < 4 * 49 * 8; c += 256) {
    int h_l = c / (49 * 8);
    int r2 = c - h_l * (49 * 8);
    int tok = r2 >> 3, ch4 = r2 & 7;
    size_t m = base + (tok / 7) * 112 + (tok % 7);
    const unsigned short* kp = qkv + m * 768 + 256 + (hg + h_l) * 32 + ch4 * 4;
    us4 kv = *(const us4*)kp;
    us4 vv = *(const us4*)(kp + 256);
    float* kd = ks + (h_l * 49 + tok) * 32 + ch4 * 4;
    float* vd = vs + (h_l * 49 + tok) * 32 + ch4 * 4;
    kd[0] = bf2f(kv.x); kd[1] = bf2f(kv.y); kd[2] = bf2f(kv.z); kd[3] = bf2f(kv.w);
    vd[0] = bf2f(vv.x); vd[1] = bf2f(vv.y); vd[2] = bf2f(vv.z); vd[3] = bf2f(vv.w);
  }

  const int lane = tid & 63;
  const int h_l = tid >> 6;
  const int h = hg + h_l;
  const int qi = lane < 49 ? lane : 48;
  const size_t mq = base + (qi / 7) * 112 + (qi % 7);

  f32x4 q[8];
  {
    const unsigned short* qp = qkv + mq * 768 + h * 32;
    const float qsc = 0.17677669529663689f;  // 1/sqrt(32)
#pragma unroll
    for (int j = 0; j < 8; j++) {
      us4 v = *(const us4*)(qp + j * 4);
      q[j].x = bf2f(v.x) * qsc; q[j].y = bf2f(v.y) * qsc;
      q[j].z = bf2f(v.z) * qsc; q[j].w = bf2f(v.w) * qsc;
    }
  }
  __syncthreads();

  float S[49];
  const float* kbase = ks + h_l * 49 * 32;
#pragma unroll
  for (int ki = 0; ki < 49; ki++) {
    const f32x4* kr = (const f32x4*)(kbase + ki * 32);
    f32x4 a0 = {0.f, 0.f, 0.f, 0.f}, a1 = {0.f, 0.f, 0.f, 0.f};
#pragma unroll
    for (int j = 0; j < 4; j++) {
      a0 += q[2 * j] * kr[2 * j];
      a1 += q[2 * j + 1] * kr[2 * j + 1];
    }
    f32x4 as = a0 + a1;
    S[ki] = (as.x + as.z) + (as.y + as.w);
  }

  const int qr = qi / 7, qc = qi % 7;
  const float* rp = rpet + h_l * 169;
#pragma unroll
  for (int ki = 0; ki < 49; ki++) {
    int ridx = (qr - ki / 7 + 6) * 13 + (qc - ki % 7 + 6);
    S[ki] += rp[ridx];
  }
  float mx = S[0];
#pragma unroll
  for (int ki = 1; ki < 49; ki++) mx = fmaxf(mx, S[ki]);
  float sum = 0.f;
#pragma unroll
  for (int ki = 0; ki < 49; ki++) {
    float e = __expf(S[ki] - mx);
    S[ki] = e;
    sum += e;
  }
  float inv = 1.f / sum;

  f32x4 o[8];
#pragma unroll
  for (int j = 0; j < 8; j++) o[j] = f32x4{0.f, 0.f, 0.f, 0.f};
  const float* vbase = vs + h_l * 49 * 32;
#pragma unroll
  for (int k = 0; k < 49; k++) {
    const f32x4* vr = (const f32x4*)(vbase + k * 32);
    float p = S[k];
#pragma unroll
    for (int j = 0; j < 8; j++) o[j] += p * vr[j];
  }
#pragma unroll
  for (int j = 0; j < 8; j++) o[j] *= inv;

  if (lane < 49) {
    unsigned short* op = y2 + mq * 256 + h * 32;
#pragma unroll
    for (int j2 = 0; j2 < 4; j2++) {
      us8 pk;
      pk[0] = f2bf(o[2 * j2].x); pk[1] = f2bf(o[2 * j2].y);
      pk[2] = f2bf(o[2 * j2].z); pk[3] = f2bf(o[2 * j2].w);
      pk[4] = f2bf(o[2 * j2 + 1].x); pk[5] = f2bf(o[2 * j2 + 1].y);
      pk[6] = f2bf(o[2 * j2 + 1].z); pk[7] = f2bf(o[2 * j2 + 1].w);
      *((us8*)(op + j2 * 8)) = pk;
    }
  }
}

// ---------------- depthwise 3x3 + bias + BN + GELU, pixel-pair row-sweep ----------------
// R17: pixel PAIRS halve rotation movs and loop overhead. Invalid rows handled by
// clamped pointers + zeroed weights (branch-free loads). VGPR ~60, no spill risk.
__global__ __launch_bounds__(256) void dwconv_kernel(
    const unsigned short* __restrict__ h1, const float* __restrict__ wT,
    const float* __restrict__ bias, const float* __restrict__ bng,
    const float* __restrict__ bnb, unsigned short* __restrict__ h2) {
  const int blk = blockIdx.x;
  const int q = blk & 3;
  const int y = (blk >> 2) % 112;
  const int b = blk / (4 * 112);
  const int tid = threadIdx.x;
  const int c0 = tid * 4;
  const int x0 = q * 28;

  f32x4 wv[9];
#pragma unroll
  for (int wi = 0; wi < 9; wi++) wv[wi] = *(const f32x4*)(wT + wi * HID_ + c0);

  const float bnrs = 0.9999950000374997f;
  f32x4 bv = ((const f32x4*)bias)[tid];
  f32x4 sc = ((const f32x4*)bng)[tid];
  sc *= bnrs;
  f32x4 sh = ((const f32x4*)bnb)[tid];
  sh += bv * sc;

  const unsigned short* rp[3];
#pragma unroll
  for (int r = 0; r < 3; r++) {
    int yy = y - 1 + r;
    if ((unsigned)yy >= 112u) {
      yy = y;
      wv[r * 3 + 0] = f32x4{0.f, 0.f, 0.f, 0.f};
      wv[r * 3 + 1] = f32x4{0.f, 0.f, 0.f, 0.f};
      wv[r * 3 + 2] = f32x4{0.f, 0.f, 0.f, 0.f};
    }
    rp[r] = h1 + ((size_t)b * HW_ + (size_t)yy * 112 + x0) * HID_ + c0;
  }

  auto ld = [&](const unsigned short* p) -> f32x4 {
    us4 v = *(const us4*)p;
    f32x4 f;
    f.x = bf2f(v.x); f.y = bf2f(v.y); f.z = bf2f(v.z); f.w = bf2f(v.w);
    return f;
  };

  f32x4 cA[3], cB[3], cC[3], cD[3];
  if (x0 > 0) {
#pragma unroll
    for (int r = 0; r < 3; r++) cA[r] = ld(rp[r] - HID_);
  } else {
#pragma unroll
    for (int r = 0; r < 3; r++) cA[r] = f32x4{0.f, 0.f, 0.f, 0.f};
  }
#pragma unroll
  for (int r = 0; r < 3; r++) cB[r] = ld(rp[r]);

  unsigned short* outp = h2 + ((size_t)b * HW_ + (size_t)y * 112 + x0) * HID_ + c0;

  auto emit = [&](const f32x4* l, const f32x4* m, const f32x4* rr,
                  unsigned short* op) {
    f32x4 a = {0.f, 0.f, 0.f, 0.f};
#pragma unroll
    for (int r = 0; r < 3; r++) {
      a += l[r] * wv[r * 3 + 0];
      a += m[r] * wv[r * 3 + 1];
      a += rr[r] * wv[r * 3 + 2];
    }
    a = a * sc + sh;
    us4 o;
    o.x = f2bf(gelu_f(a.x));
    o.y = f2bf(gelu_f(a.y));
    o.z = f2bf(gelu_f(a.z));
    o.w = f2bf(gelu_f(a.w));
    *(us4*)op = o;
  };

  // 14 pixel-pairs; pairs 0..12 have unconditionally valid loads (x+2 <= 110)
#pragma unroll 2
  for (int k = 0; k < 13; ++k) {
#pragma unroll
    for (int r = 0; r < 3; r++) {
      cC[r] = ld(rp[r] + (size_t)(2 * k + 1) * HID_);
      cD[r] = ld(rp[r] + (size_t)(2 * k + 2) * HID_);
    }
    emit(cA, cB, cC, outp + (size_t)(2 * k) * HID_);
    emit(cB, cC, cD, outp + (size_t)(2 * k + 1) * HID_);
#pragma unroll
    for (int r = 0; r < 3; r++) { cA[r] = cC[r]; cB[r] = cD[r]; }
  }
  // last pair (x = x0+26, x0+27): right neighbor of x0+27 exists unless q == 3
#pragma unroll
  for (int r = 0; r < 3; r++) cC[r] = ld(rp[r] + (size_t)27 * HID_);
  if (x0 + 28 < 112) {
#pragma unroll
    for (int r = 0; r < 3; r++) cD[r] = ld(rp[r] + (size_t)28 * HID_);
  } else {
#pragma unroll
    for (int r = 0; r < 3; r++) cD[r] = f32x4{0.f, 0.f, 0.f, 0.f};
  }
  emit(cA, cB, cC, outp + (size_t)26 * HID_);
  emit(cB, cC, cD, outp + (size_t)27 * HID_);
}

extern "C" void kernel_launch(void* const* d_in, const int* in_sizes, int n_in,
                              void* d_out, int out_size, void* d_ws, size_t ws_size,
                              hipStream_t stream) {
  const float* x      = (const float*)d_in[0];
  const float* ln1_g  = (const float*)d_in[1];
  const float* ln1_b  = (const float*)d_in[2];
  const float* qkv_w  = (const float*)d_in[3];
  const float* qkv_b  = (const float*)d_in[4];
  const float* rpe    = (const float*)d_in[5];
  const float* proj_w = (const float*)d_in[6];
  const float* proj_b = (const float*)d_in[7];
  const float* ln2_g  = (const float*)d_in[8];
  const float* ln2_b  = (const float*)d_in[9];
  const float* c1_w   = (const float*)d_in[10];
  const float* c1_b   = (const float*)d_in[11];
  const float* bn1_g  = (const float*)d_in[12];
  const float* bn1_b  = (const float*)d_in[13];
  const float* dw_w   = (const float*)d_in[14];
  const float* dw_b   = (const float*)d_in[15];
  const float* bn2_g  = (const float*)d_in[16];
  const float* bn2_b  = (const float*)d_in[17];
  const float* c3_w   = (const float*)d_in[18];
  const float* c3_b   = (const float*)d_in[19];
  const float* bn3_g  = (const float*)d_in[20];
  const float* bn3_b  = (const float*)d_in[21];

  // ---- workspace layout (liveness-aliased; t bf16) ----
  char* ws = (char*)d_ws;
  size_t off = 0;
  unsigned short* t = (unsigned short*)(ws + off);  off += (size_t)M_ * 256 * 2;
  unsigned short* S1 = (unsigned short*)(ws + off); off += (size_t)M_ * 1024 * 2;
  unsigned short* S2 = (unsigned short*)(ws + off); off += (size_t)M_ * 1024 * 2;
  unsigned short* yb = S2;  // alias: never live at the same time as S2
  unsigned short* wb_qkv  = (unsigned short*)(ws + off); off += (size_t)2 * 768 * 256 * 2;
  unsigned short* wb_proj = (unsigned short*)(ws + off); off += (size_t)2 * 256 * 256 * 2;
  unsigned short* wb_c1   = (unsigned short*)(ws + off); off += (size_t)2 * 1024 * 256 * 2;
  unsigned short* wb_c3   = (unsigned short*)(ws + off); off += (size_t)2 * 256 * 1024 * 2;
  float* wT = (float*)(ws + off);                   off += (size_t)2 * HID_ * 9 * 4;
  if (off > ws_size) return;  // clean failure instead of OOB crash

  // weight prep
  cast_bf16_kernel<<<384, 256, 0, stream>>>(qkv_w, wb_qkv, 2 * 768 * 256 / 4);
  cast_bf16_kernel<<<128, 256, 0, stream>>>(proj_w, wb_proj, 2 * 256 * 256 / 4);
  cast_bf16_kernel<<<512, 256, 0, stream>>>(c1_w, wb_c1, 2 * 1024 * 256 / 4);
  cast_bf16_kernel<<<512, 256, 0, stream>>>(c3_w, wb_c3, 2 * 256 * 1024 / 4);
  dwT_kernel<<<72, 256, 0, stream>>>(dw_w, wT);

  transpose_in_kernel<<<dim3(392, 8, 4), dim3(32, 8), 0, stream>>>(x, t);

  for (int i = 0; i < 2; i++) {
    ln_kernel<<<M_ / 4, 256, 0, stream>>>(t, ln1_g + i * 256, ln1_b + i * 256, yb);
    gemm_kernel<0><<<dim3(6, 392), 256, 0, stream>>>(
        yb, wb_qkv + (size_t)i * 768 * 256, qkv_b + i * 768, nullptr, nullptr,
        nullptr, S1, 768, 256);
    attn_kernel<<<2048, 256, 0, stream>>>(S1, rpe + (size_t)i * 169 * 8, yb);
    gemm_kernel<1><<<dim3(2, 392), 256, 0, stream>>>(
        yb, wb_proj + (size_t)i * 256 * 256, proj_b + i * 256, nullptr, nullptr,
        t, nullptr, 256, 256);
    ln_kernel<<<M_ / 4, 256, 0, stream>>>(t, ln2_g + i * 256, ln2_b + i * 256, yb);
    gemm_kernel<2><<<dim3(8, 392), 256, 0, stream>>>(
        yb, wb_c1 + (size_t)i * 1024 * 256, c1_b + i * 1024, bn1_g + i * 1024,
        bn1_b + i * 1024, nullptr, S1, 1024, 256);
    dwconv_kernel<<<4 * 112 * 4, 256, 0, stream>>>(S1, wT + (size_t)i * HID_ * 9,
                                                   dw_b + i * 1024, bn2_g + i * 1024,
                                                   bn2_b + i * 1024, S2);
    gemm_kernel<3><<<dim3(2, 392), 256, 0, stream>>>(
        S2, wb_c3 + (size_t)i * 256 * 1024, c3_b + i * 256, bn3_g + i * 256,
        bn3_b + i * 256, t, nullptr, 256, 1024);
  }

  transpose_out_kernel<<<dim3(392, 8, 4), dim3(32, 8), 0, stream>>>(t, (float*)d_out);
}

// Round 20
// 659.712 us; speedup vs baseline: 7.5017x; 1.0169x over previous
//
#include <hip/hip_runtime.h>

typedef __attribute__((ext_vector_type(4))) float f32x4;
typedef __attribute__((ext_vector_type(8))) __bf16 bf16x8;
typedef __attribute__((ext_vector_type(4))) unsigned short us4;
typedef __attribute__((ext_vector_type(8))) unsigned short us8;

#define DEVI static __device__ __forceinline__

constexpr int C_   = 256;
constexpr int HW_  = 112 * 112;   // 12544
constexpr int M_   = 4 * HW_;     // 50176 tokens
constexpr int HID_ = 1024;

// native bf16 convert (RNE) -> compiler emits v_cvt_pk_bf16_f32 where possible
DEVI unsigned short f2bf(float f) {
  __bf16 h = (__bf16)f;
  return __builtin_bit_cast(unsigned short, h);
}
DEVI float bf2f(unsigned short s) { return __uint_as_float(((unsigned)s) << 16); }
// tanh-form GELU via v_exp_f32 (~9 VALU vs ~25 for erff); max dev ~3e-4
DEVI float gelu_f(float x) {
  float u = x * (0.7978845608028654f + 0.0356774081363001f * x * x);
  float e = __expf(2.f * u);
  float t = 1.f - 2.f / (e + 1.f);
  return 0.5f * x * (1.f + t);
}

// ---------------- fused weight prep: 4 bf16 casts + dw transpose, ONE launch ----------------
// blockIdx ranges (all job sizes exact multiples of 256, no bounds checks):
//   [0,384)    qkv cast   (98304 f32x4)
//   [384,512)  proj cast  (32768 f32x4)
//   [512,1024) c1 cast    (131072 f32x4)
//   [1024,1536) c3 cast   (131072 f32x4)
//   [1536,1608) dwT       (18432 scalars)
__global__ void prep_kernel(const float* __restrict__ qkv_w, const float* __restrict__ proj_w,
                            const float* __restrict__ c1_w, const float* __restrict__ c3_w,
                            const float* __restrict__ dw_w,
                            unsigned short* __restrict__ wb_qkv, unsigned short* __restrict__ wb_proj,
                            unsigned short* __restrict__ wb_c1, unsigned short* __restrict__ wb_c3,
                            float* __restrict__ wT) {
  const int blk = blockIdx.x, tid = threadIdx.x;
  if (blk < 1536) {
    const float* src;
    unsigned short* dst;
    int i;
    if (blk < 384)       { src = qkv_w;  dst = wb_qkv;  i = blk * 256 + tid; }
    else if (blk < 512)  { src = proj_w; dst = wb_proj; i = (blk - 384) * 256 + tid; }
    else if (blk < 1024) { src = c1_w;   dst = wb_c1;   i = (blk - 512) * 256 + tid; }
    else                 { src = c3_w;   dst = wb_c3;   i = (blk - 1024) * 256 + tid; }
    f32x4 v = ((const f32x4*)src)[i];
    us4 o;
    o.x = f2bf(v.x); o.y = f2bf(v.y); o.z = f2bf(v.z); o.w = f2bf(v.w);
    ((us4*)dst)[i] = o;
  } else {
    int i = (blk - 1536) * 256 + tid;  // < 18432 exactly
    int blkI = i / (HID_ * 9), rem = i % (HID_ * 9);
    int c = rem / 9, wi = rem % 9;
    wT[blkI * HID_ * 9 + wi * HID_ + c] = dw_w[i];
  }
}

// ---------------- (B,C,HW) fp32 -> (B,HW,C) bf16 residual ----------------
__global__ void transpose_in_kernel(const float* __restrict__ x,
                                    unsigned short* __restrict__ t) {
  __shared__ float tile[32][33];
  int b = blockIdx.z;
  int p0 = blockIdx.x * 32, c0 = blockIdx.y * 32;
  int tx = threadIdx.x, ty = threadIdx.y;
  const float* xb = x + (size_t)b * C_ * HW_;
#pragma unroll
  for (int i = 0; i < 4; i++)
    tile[ty + 8 * i][tx] = xb[(size_t)(c0 + ty + 8 * i) * HW_ + p0 + tx];
  __syncthreads();
  unsigned short* tb = t + (size_t)b * HW_ * C_;
#pragma unroll
  for (int i = 0; i < 4; i++)
    tb[(size_t)(p0 + ty + 8 * i) * C_ + c0 + tx] = f2bf(tile[tx][ty + 8 * i]);
}

// ---------------- (B,HW,C) bf16 -> (B,C,HW) fp32 output ----------------
__global__ void transpose_out_kernel(const unsigned short* __restrict__ t,
                                     float* __restrict__ out) {
  __shared__ float tile[32][33];
  int b = blockIdx.z;
  int p0 = blockIdx.x * 32, c0 = blockIdx.y * 32;
  int tx = threadIdx.x, ty = threadIdx.y;
  const unsigned short* tb = t + (size_t)b * HW_ * C_;
#pragma unroll
  for (int i = 0; i < 4; i++)
    tile[ty + 8 * i][tx] = bf2f(tb[(size_t)(p0 + ty + 8 * i) * C_ + c0 + tx]);
  __syncthreads();
  float* ob = out + (size_t)b * C_ * HW_;
#pragma unroll
  for (int i = 0; i < 4; i++)
    ob[(size_t)(c0 + ty + 8 * i) * HW_ + p0 + tx] = tile[tx][ty + 8 * i];
}

// ---------------- LayerNorm (bf16 in, bf16 out), one wave per row ----------------
__global__ void ln_kernel(const unsigned short* __restrict__ t, const float* __restrict__ g,
                          const float* __restrict__ bsh, unsigned short* __restrict__ out) {
  int row = blockIdx.x * 4 + (threadIdx.x >> 6);
  int lane = threadIdx.x & 63;
  const unsigned short* tr = t + (size_t)row * C_;
  us4 v4 = ((const us4*)tr)[lane];
  f32x4 v;
  v.x = bf2f(v4.x); v.y = bf2f(v4.y); v.z = bf2f(v4.z); v.w = bf2f(v4.w);
  float s  = v.x + v.y + v.z + v.w;
  float s2 = v.x * v.x + v.y * v.y + v.z * v.z + v.w * v.w;
#pragma unroll
  for (int off = 1; off < 64; off <<= 1) {
    s  += __shfl_xor(s, off);
    s2 += __shfl_xor(s2, off);
  }
  float mean = s * (1.f / 256.f);
  float var  = s2 * (1.f / 256.f) - mean * mean;
  float rstd = rsqrtf(var + 1e-6f);
  f32x4 gg = ((const f32x4*)g)[lane];
  f32x4 bb = ((const f32x4*)bsh)[lane];
  us4 o;
  o.x = f2bf((v.x - mean) * rstd * gg.x + bb.x);
  o.y = f2bf((v.y - mean) * rstd * gg.y + bb.y);
  o.z = f2bf((v.z - mean) * rstd * gg.z + bb.z);
  o.w = f2bf((v.w - mean) * rstd * gg.w + bb.w);
  ((us4*)(out + (size_t)row * C_))[lane] = o;
}

// ---------------- GEMM: out(M,N) = A(M,K) * Wt(N,K)^T, bf16 in, fp32 acc ----------------
// 128x128 block tile, 4 waves (2x2, 64x64 each), 3 LDS buffers (48KB -> 3 blocks/CU),
// depth-2 prefetch, counted vmcnt(4). XCD-chunked swizzle for A-panel L2 reuse.
// ALL epilogues staged through LDS -> 16B/lane coalesced I/O.
template <int EPI>
__global__ __launch_bounds__(256, 2) void gemm_kernel(
    const unsigned short* __restrict__ A, const unsigned short* __restrict__ Wt,
    const float* __restrict__ bias, const float* __restrict__ bng,
    const float* __restrict__ bnb, unsigned short* __restrict__ resid,
    unsigned short* __restrict__ outb, int N, int K) {
  // per buffer: A[128*32] shorts @0, B[128*32] shorts @4096; 8192 shorts = 16KB
  __shared__ unsigned short smem[3 * 8192];
  const int tid = threadIdx.x;
  const int wave = tid >> 6, lane = tid & 63;

  // XCD-chunked swizzle (all grids have nwg % 8 == 0)
  const int bnN = gridDim.x;
  const int nwg = bnN * gridDim.y;
  int wg = blockIdx.y * bnN + blockIdx.x;
  const int chunk = nwg >> 3;
  wg = (wg & 7) * chunk + (wg >> 3);
  const int bn = wg % bnN;
  const int bm = wg / bnN;

  const int wm = wave >> 1, wn = wave & 1;
  const int laneRow = lane >> 2;      // 0..15
  const int scol = (lane & 3) * 8;    // shorts (16B per lane)
  const size_t aBase = (size_t)bm * 128;
  const size_t bBase = (size_t)bn * 128;

  f32x4 acc[4][4];
#pragma unroll
  for (int i = 0; i < 4; i++)
#pragma unroll
    for (int j = 0; j < 4; j++) acc[i][j] = f32x4{0.f, 0.f, 0.f, 0.f};

  auto stage = [&](int buf, int kt) {
    const int k0 = kt << 5;
    unsigned short* sb = smem + buf * 8192;
#pragma unroll
    for (int r = 0; r < 2; ++r) {
      int row = wave * 32 + r * 16 + laneRow;
      __builtin_amdgcn_global_load_lds(
          (const __attribute__((address_space(1))) void*)(A + (aBase + row) * K + k0 + scol),
          (__attribute__((address_space(3))) void*)(sb + row * 32 + scol), 16, 0, 0);
    }
#pragma unroll
    for (int r = 0; r < 2; ++r) {
      int row = wave * 32 + r * 16 + laneRow;
      __builtin_amdgcn_global_load_lds(
          (const __attribute__((address_space(1))) void*)(Wt + (bBase + row) * K + k0 + scol),
          (__attribute__((address_space(3))) void*)(sb + 4096 + row * 32 + scol), 16, 0, 0);
    }
  };

  const int nK = K >> 5;
  stage(0, 0);
  if (nK > 1) {
    stage(1, 1);
    asm volatile("s_waitcnt vmcnt(4)" ::: "memory");
  } else {
    asm volatile("s_waitcnt vmcnt(0)" ::: "memory");
  }
  __builtin_amdgcn_s_barrier();
  asm volatile("" ::: "memory");

  const int fr = lane & 15, kh = (lane >> 4) * 8;
  for (int kt = 0; kt < nK; ++kt) {
    const int cur = kt % 3;
    const bool more2 = (kt + 2 < nK);
    if (more2) stage((kt + 2) % 3, kt + 2);  // depth-2 prefetch flies over compute

    const unsigned short* sb = smem + cur * 8192;
    bf16x8 af[4], bfr[4];
#pragma unroll
    for (int mi = 0; mi < 4; mi++)
      af[mi] = *(const bf16x8*)(sb + (wm * 64 + mi * 16 + fr) * 32 + kh);
#pragma unroll
    for (int ni = 0; ni < 4; ni++)
      bfr[ni] = *(const bf16x8*)(sb + 4096 + (wn * 64 + ni * 16 + fr) * 32 + kh);
#pragma unroll
    for (int mi = 0; mi < 4; mi++)
#pragma unroll
      for (int ni = 0; ni < 4; ni++)
        acc[mi][ni] = __builtin_amdgcn_mfma_f32_16x16x32_bf16(af[mi], bfr[ni], acc[mi][ni], 0, 0, 0);

    if (kt + 1 < nK) {
      if (more2) {
        asm volatile("s_waitcnt vmcnt(4)" ::: "memory");  // retire tile kt+1 only
      } else {
        asm volatile("s_waitcnt vmcnt(0)" ::: "memory");  // boundary drain (once)
      }
      __builtin_amdgcn_s_barrier();
      asm volatile("" ::: "memory");
    }
  }

  const int r4 = (lane >> 4) * 4;
  const float bnrs = 0.9999950000374997f;  // rsqrt(1 + 1e-5)

  // --- staged epilogue: LDS tile [128][128] shorts with row-XOR swizzle ---
  __syncthreads();  // all waves done reading K-loop smem
  unsigned short* esm = smem;  // 16384 shorts = 32KB <= 48KB
#pragma unroll
  for (int ni = 0; ni < 4; ni++) {
    int cl = wn * 64 + ni * 16 + fr;       // local col 0..127
    int cg = bn * 128 + cl;                // global col
    float bval = bias[cg];
    float sc = 0.f, sh = 0.f;
    if (EPI == 2 || EPI == 3) { sc = bng[cg] * bnrs; sh = bnb[cg]; }
#pragma unroll
    for (int mi = 0; mi < 4; mi++) {
#pragma unroll
      for (int j = 0; j < 4; j++) {
        int row = wm * 64 + mi * 16 + r4 + j;
        float v = acc[mi][ni][j] + bval;
        if (EPI == 2 || EPI == 3) v = gelu_f(v * sc + sh);
        esm[row * 128 + (cl ^ (((row >> 2) & 3) << 4))] = f2bf(v);
      }
    }
  }
  __syncthreads();
#pragma unroll
  for (int it = 0; it < 8; it++) {
    int idx = it * 256 + tid;
    int row = idx >> 4;
    int c0 = (idx & 15) * 8;
    int c0s = c0 ^ (((row >> 2) & 3) << 4);
    us8 v = *(const us8*)(esm + row * 128 + c0s);
    if (EPI == 0 || EPI == 2) {
      *(us8*)(outb + (aBase + row) * (size_t)N + bn * 128 + c0) = v;
    } else {
      // residual RMW on bf16 stream (N == 256), fully coalesced 16B/lane
      unsigned short* rp = resid + (aBase + row) * 256 + bn * 128 + c0;
      us8 tv = *(const us8*)rp;
      us8 o;
#pragma unroll
      for (int e = 0; e < 8; e++) o[e] = f2bf(bf2f(tv[e]) + bf2f(v[e]));
      *(us8*)rp = o;
    }
  }
}

// ---------------- windowed attention, register-resident (R13-proven) ----------------
// K,V f32 in LDS (25KB+25KB); rpe staged for ONLY this block's 4 heads (2.7KB)
// -> 51.7KB LDS -> 3 blocks/CU. VGPR 76, no spill (R13-verified, 78.7us).
// R9/R10/R14 lesson: ANY restructure adding concurrent live state spills. Do not touch.
__global__ __launch_bounds__(256, 2) void attn_kernel(const unsigned short* __restrict__ qkv,
                                                      const float* __restrict__ rpe,
                                                      unsigned short* __restrict__ y2) {
  __shared__ float ks[4 * 49 * 32];
  __shared__ float vs[4 * 49 * 32];
  __shared__ float rpet[4 * 169];  // [h_l][ridx]
  const int tid = threadIdx.x;
  const int blk = blockIdx.x;
  const int win = blk >> 1;
  const int hg = (blk & 1) * 4;
  const int b = win >> 8, rem = win & 255;
  const int ph = rem >> 4, pw = rem & 15;
  const size_t base = (size_t)b * HW_ + ph * 7 * 112 + pw * 7;

  for (int c = tid; c < 169 * 4; c += 256)
    rpet[(c & 3) * 169 + (c >> 2)] = rpe[(c >> 2) * 8 + hg + (c & 3)];
  for (int c = tid; c < 4 * 49 * 8; c += 256) {
    int h_l = c / (49 * 8);
    int r2 = c - h_l * (49 * 8);
    int tok = r2 >> 3, ch4 = r2 & 7;
    size_t m = base + (tok / 7) * 112 + (tok % 7);
    const unsigned short* kp = qkv + m * 768 + 256 + (hg + h_l) * 32 + ch4 * 4;
    us4 kv = *(const us4*)kp;
    us4 vv = *(const us4*)(kp + 256);
    float* kd = ks + (h_l * 49 + tok) * 32 + ch4 * 4;
    float* vd = vs + (h_l * 49 + tok) * 32 + ch4 * 4;
    kd[0] = bf2f(kv.x); kd[1] = bf2f(kv.y); kd[2] = bf2f(kv.z); kd[3] = bf2f(kv.w);
    vd[0] = bf2f(vv.x); vd[1] = bf2f(vv.y); vd[2] = bf2f(vv.z); vd[3] = bf2f(vv.w);
  }

  const int lane = tid & 63;
  const int h_l = tid >> 6;
  const int h = hg + h_l;
  const int qi = lane < 49 ? lane : 48;
  const size_t mq = base + (qi / 7) * 112 + (qi % 7);

  f32x4 q[8];
  {
    const unsigned short* qp = qkv + mq * 768 + h * 32;
    const float qsc = 0.17677669529663689f;  // 1/sqrt(32)
#pragma unroll
    for (int j = 0; j < 8; j++) {
      us4 v = *(const us4*)(qp + j * 4);
      q[j].x = bf2f(v.x) * qsc; q[j].y = bf2f(v.y) * qsc;
      q[j].z = bf2f(v.z) * qsc; q[j].w = bf2f(v.w) * qsc;
    }
  }
  __syncthreads();

  float S[49];
  const float* kbase = ks + h_l * 49 * 32;
#pragma unroll
  for (int ki = 0; ki < 49; ki++) {
    const f32x4* kr = (const f32x4*)(kbase + ki * 32);
    f32x4 a0 = {0.f, 0.f, 0.f, 0.f}, a1 = {0.f, 0.f, 0.f, 0.f};
#pragma unroll
    for (int j = 0; j < 4; j++) {
      a0 += q[2 * j] * kr[2 * j];
      a1 += q[2 * j + 1] * kr[2 * j + 1];
    }
    f32x4 as = a0 + a1;
    S[ki] = (as.x + as.z) + (as.y + as.w);
  }

  const int qr = qi / 7, qc = qi % 7;
  const float* rp = rpet + h_l * 169;
#pragma unroll
  for (int ki = 0; ki < 49; ki++) {
    int ridx = (qr - ki / 7 + 6) * 13 + (qc - ki % 7 + 6);
    S[ki] += rp[ridx];
  }
  float mx = S[0];
#pragma unroll
  for (int ki = 1; ki < 49; ki++) mx = fmaxf(mx, S[ki]);
  float sum = 0.f;
#pragma unroll
  for (int ki = 0; ki < 49; ki++) {
    float e = __expf(S[ki] - mx);
    S[ki] = e;
    sum += e;
  }
  float inv = 1.f / sum;

  f32x4 o[8];
#pragma unroll
  for (int j = 0; j < 8; j++) o[j] = f32x4{0.f, 0.f, 0.f, 0.f};
  const float* vbase = vs + h_l * 49 * 32;
#pragma unroll
  for (int k = 0; k < 49; k++) {
    const f32x4* vr = (const f32x4*)(vbase + k * 32);
    float p = S[k];
#pragma unroll
    for (int j = 0; j < 8; j++) o[j] += p * vr[j];
  }
#pragma unroll
  for (int j = 0; j < 8; j++) o[j] *= inv;

  if (lane < 49) {
    unsigned short* op = y2 + mq * 256 + h * 32;
#pragma unroll
    for (int j2 = 0; j2 < 4; j2++) {
      us8 pk;
      pk[0] = f2bf(o[2 * j2].x); pk[1] = f2bf(o[2 * j2].y);
      pk[2] = f2bf(o[2 * j2].z); pk[3] = f2bf(o[2 * j2].w);
      pk[4] = f2bf(o[2 * j2 + 1].x); pk[5] = f2bf(o[2 * j2 + 1].y);
      pk[6] = f2bf(o[2 * j2 + 1].z); pk[7] = f2bf(o[2 * j2 + 1].w);
      *((us8*)(op + j2 * 8)) = pk;
    }
  }
}

// ---------------- depthwise 3x3 + bias + BN + GELU, pixel-pair row-sweep ----------------
// R17: pixel PAIRS halve rotation movs and loop overhead. Invalid rows handled by
// clamped pointers + zeroed weights (branch-free loads). VGPR ~60, no spill risk.
__global__ __launch_bounds__(256) void dwconv_kernel(
    const unsigned short* __restrict__ h1, const float* __restrict__ wT,
    const float* __restrict__ bias, const float* __restrict__ bng,
    const float* __restrict__ bnb, unsigned short* __restrict__ h2) {
  const int blk = blockIdx.x;
  const int q = blk & 3;
  const int y = (blk >> 2) % 112;
  const int b = blk / (4 * 112);
  const int tid = threadIdx.x;
  const int c0 = tid * 4;
  const int x0 = q * 28;

  f32x4 wv[9];
#pragma unroll
  for (int wi = 0; wi < 9; wi++) wv[wi] = *(const f32x4*)(wT + wi * HID_ + c0);

  const float bnrs = 0.9999950000374997f;
  f32x4 bv = ((const f32x4*)bias)[tid];
  f32x4 sc = ((const f32x4*)bng)[tid];
  sc *= bnrs;
  f32x4 sh = ((const f32x4*)bnb)[tid];
  sh += bv * sc;

  const unsigned short* rp[3];
#pragma unroll
  for (int r = 0; r < 3; r++) {
    int yy = y - 1 + r;
    if ((unsigned)yy >= 112u) {
      yy = y;
      wv[r * 3 + 0] = f32x4{0.f, 0.f, 0.f, 0.f};
      wv[r * 3 + 1] = f32x4{0.f, 0.f, 0.f, 0.f};
      wv[r * 3 + 2] = f32x4{0.f, 0.f, 0.f, 0.f};
    }
    rp[r] = h1 + ((size_t)b * HW_ + (size_t)yy * 112 + x0) * HID_ + c0;
  }

  auto ld = [&](const unsigned short* p) -> f32x4 {
    us4 v = *(const us4*)p;
    f32x4 f;
    f.x = bf2f(v.x); f.y = bf2f(v.y); f.z = bf2f(v.z); f.w = bf2f(v.w);
    return f;
  };

  f32x4 cA[3], cB[3], cC[3], cD[3];
  if (x0 > 0) {
#pragma unroll
    for (int r = 0; r < 3; r++) cA[r] = ld(rp[r] - HID_);
  } else {
#pragma unroll
    for (int r = 0; r < 3; r++) cA[r] = f32x4{0.f, 0.f, 0.f, 0.f};
  }
#pragma unroll
  for (int r = 0; r < 3; r++) cB[r] = ld(rp[r]);

  unsigned short* outp = h2 + ((size_t)b * HW_ + (size_t)y * 112 + x0) * HID_ + c0;

  auto emit = [&](const f32x4* l, const f32x4* m, const f32x4* rr,
                  unsigned short* op) {
    f32x4 a = {0.f, 0.f, 0.f, 0.f};
#pragma unroll
    for (int r = 0; r < 3; r++) {
      a += l[r] * wv[r * 3 + 0];
      a += m[r] * wv[r * 3 + 1];
      a += rr[r] * wv[r * 3 + 2];
    }
    a = a * sc + sh;
    us4 o;
    o.x = f2bf(gelu_f(a.x));
    o.y = f2bf(gelu_f(a.y));
    o.z = f2bf(gelu_f(a.z));
    o.w = f2bf(gelu_f(a.w));
    *(us4*)op = o;
  };

  // 14 pixel-pairs; pairs 0..12 have unconditionally valid loads (x+2 <= 110)
#pragma unroll 2
  for (int k = 0; k < 13; ++k) {
#pragma unroll
    for (int r = 0; r < 3; r++) {
      cC[r] = ld(rp[r] + (size_t)(2 * k + 1) * HID_);
      cD[r] = ld(rp[r] + (size_t)(2 * k + 2) * HID_);
    }
    emit(cA, cB, cC, outp + (size_t)(2 * k) * HID_);
    emit(cB, cC, cD, outp + (size_t)(2 * k + 1) * HID_);
#pragma unroll
    for (int r = 0; r < 3; r++) { cA[r] = cC[r]; cB[r] = cD[r]; }
  }
  // last pair (x = x0+26, x0+27): right neighbor of x0+27 exists unless q == 3
#pragma unroll
  for (int r = 0; r < 3; r++) cC[r] = ld(rp[r] + (size_t)27 * HID_);
  if (x0 + 28 < 112) {
#pragma unroll
    for (int r = 0; r < 3; r++) cD[r] = ld(rp[r] + (size_t)28 * HID_);
  } else {
#pragma unroll
    for (int r = 0; r < 3; r++) cD[r] = f32x4{0.f, 0.f, 0.f, 0.f};
  }
  emit(cA, cB, cC, outp + (size_t)26 * HID_);
  emit(cB, cC, cD, outp + (size_t)27 * HID_);
}

extern "C" void kernel_launch(void* const* d_in, const int* in_sizes, int n_in,
                              void* d_out, int out_size, void* d_ws, size_t ws_size,
                              hipStream_t stream) {
  const float* x      = (const float*)d_in[0];
  const float* ln1_g  = (const float*)d_in[1];
  const float* ln1_b  = (const float*)d_in[2];
  const float* qkv_w  = (const float*)d_in[3];
  const float* qkv_b  = (const float*)d_in[4];
  const float* rpe    = (const float*)d_in[5];
  const float* proj_w = (const float*)d_in[6];
  const float* proj_b = (const float*)d_in[7];
  const float* ln2_g  = (const float*)d_in[8];
  const float* ln2_b  = (const float*)d_in[9];
  const float* c1_w   = (const float*)d_in[10];
  const float* c1_b   = (const float*)d_in[11];
  const float* bn1_g  = (const float*)d_in[12];
  const float* bn1_b  = (const float*)d_in[13];
  const float* dw_w   = (const float*)d_in[14];
  const float* dw_b   = (const float*)d_in[15];
  const float* bn2_g  = (const float*)d_in[16];
  const float* bn2_b  = (const float*)d_in[17];
  const float* c3_w   = (const float*)d_in[18];
  const float* c3_b   = (const float*)d_in[19];
  const float* bn3_g  = (const float*)d_in[20];
  const float* bn3_b  = (const float*)d_in[21];

  // ---- workspace layout (liveness-aliased; t bf16) ----
  char* ws = (char*)d_ws;
  size_t off = 0;
  unsigned short* t = (unsigned short*)(ws + off);  off += (size_t)M_ * 256 * 2;
  unsigned short* S1 = (unsigned short*)(ws + off); off += (size_t)M_ * 1024 * 2;
  unsigned short* S2 = (unsigned short*)(ws + off); off += (size_t)M_ * 1024 * 2;
  unsigned short* yb = S2;  // alias: never live at the same time as S2
  unsigned short* wb_qkv  = (unsigned short*)(ws + off); off += (size_t)2 * 768 * 256 * 2;
  unsigned short* wb_proj = (unsigned short*)(ws + off); off += (size_t)2 * 256 * 256 * 2;
  unsigned short* wb_c1   = (unsigned short*)(ws + off); off += (size_t)2 * 1024 * 256 * 2;
  unsigned short* wb_c3   = (unsigned short*)(ws + off); off += (size_t)2 * 256 * 1024 * 2;
  float* wT = (float*)(ws + off);                   off += (size_t)2 * HID_ * 9 * 4;
  if (off > ws_size) return;  // clean failure instead of OOB crash

  // fused weight prep (was 5 launches)
  prep_kernel<<<1608, 256, 0, stream>>>(qkv_w, proj_w, c1_w, c3_w, dw_w,
                                        wb_qkv, wb_proj, wb_c1, wb_c3, wT);

  transpose_in_kernel<<<dim3(392, 8, 4), dim3(32, 8), 0, stream>>>(x, t);

  for (int i = 0; i < 2; i++) {
    ln_kernel<<<M_ / 4, 256, 0, stream>>>(t, ln1_g + i * 256, ln1_b + i * 256, yb);
    gemm_kernel<0><<<dim3(6, 392), 256, 0, stream>>>(
        yb, wb_qkv + (size_t)i * 768 * 256, qkv_b + i * 768, nullptr, nullptr,
        nullptr, S1, 768, 256);
    attn_kernel<<<2048, 256, 0, stream>>>(S1, rpe + (size_t)i * 169 * 8, yb);
    gemm_kernel<1><<<dim3(2, 392), 256, 0, stream>>>(
        yb, wb_proj + (size_t)i * 256 * 256, proj_b + i * 256, nullptr, nullptr,
        t, nullptr, 256, 256);
    ln_kernel<<<M_ / 4, 256, 0, stream>>>(t, ln2_g + i * 256, ln2_b + i * 256, yb);
    gemm_kernel<2><<<dim3(8, 392), 256, 0, stream>>>(
        yb, wb_c1 + (size_t)i * 1024 * 256, c1_b + i * 1024, bn1_g + i * 1024,
        bn1_b + i * 1024, nullptr, S1, 1024, 256);
    dwconv_kernel<<<4 * 112 * 4, 256, 0, stream>>>(S1, wT + (size_t)i * HID_ * 9,
                                                   dw_b + i * 1024, bn2_g + i * 1024,
                                                   bn2_b + i * 1024, S2);
    gemm_kernel<3><<<dim3(2, 392), 256, 0, stream>>>(
        S2, wb_c3 + (size_t)i * 256 * 1024, c3_b + i * 256, bn3_g + i * 256,
        bn3_b + i * 256, t, nullptr, 256, 1024);
  }

  transpose_out_kernel<<<dim3(392, 8, 4), dim3(32, 8), 0, stream>>>(t, (float*)d_out);
}